// Round 2
// baseline (467.008 us; speedup 1.0000x reference)
//
#include <hip/hip_runtime.h>

// Problem: x [16384, 512] f32, codebook [8192, 512] f32.
// out[n] = codebook[argmin_k ||x_n - c_k||^2]
// Strategy: bf16 MFMA GEMM for approx scores (cnorm[k] - 2 x.c), per-(row,128-col-tile)
// (min, 2ndmin, argmin) stats, then guaranteed-inclusive fp64 refinement of candidates.

#define MROWS 16384
#define KCB   8192
#define DDIM  512
#define BM 128
#define BN 128
#define BK 64
#define NKT (DDIM / BK)      // 8 K-steps
#define NTILES (KCB / BN)    // 64 column tiles
#define MARGIN 8.0f          // > 2 * worst-case bf16 score error (paranoid bound ~6.4)

typedef unsigned short u16;
typedef __attribute__((ext_vector_type(8))) short bf16x8;
typedef __attribute__((ext_vector_type(4))) float f32x4;

__device__ inline u16 f2bf(float f) {       // round-to-nearest-even f32 -> bf16
  unsigned int u = __float_as_uint(f);
  u += 0x7FFFu + ((u >> 16) & 1u);
  return (u16)(u >> 16);
}

__device__ inline void gload16(const void* g, void* l) {
  __builtin_amdgcn_global_load_lds((const __attribute__((address_space(1))) void*)g,
                                   (__attribute__((address_space(3))) void*)l,
                                   16, 0, 0);
}

__device__ inline double shfl_xor_dbl(double v, int m) {
  long long l = __double_as_longlong(v);
  int lo = (int)(l & 0xffffffffLL), hi = (int)(l >> 32);
  lo = __shfl_xor(lo, m, 64);
  hi = __shfl_xor(hi, m, 64);
  return __longlong_as_double(((long long)hi << 32) | (unsigned long long)(unsigned int)lo);
}

// merge two (min, secondmin, argmin) partial stats over disjoint column sets
__device__ inline void combine(float& a, float& b, int& i, float oa, float ob, int oi) {
  float nb = fminf(fmaxf(a, oa), fminf(b, ob));
  if (oa < a || (oa == a && oi < i)) { a = oa; i = oi; }
  b = nb;
}

// ---------------- conversion kernels ----------------

__global__ __launch_bounds__(256) void k_conv_x(const float* __restrict__ x,
                                                u16* __restrict__ xb) {
  size_t i = ((size_t)blockIdx.x * 256 + threadIdx.x) * 8;
  float4 a = *(const float4*)(x + i);
  float4 b = *(const float4*)(x + i + 4);
  union { u16 s[8]; uint4 v; } u;
  u.s[0]=f2bf(a.x); u.s[1]=f2bf(a.y); u.s[2]=f2bf(a.z); u.s[3]=f2bf(a.w);
  u.s[4]=f2bf(b.x); u.s[5]=f2bf(b.y); u.s[6]=f2bf(b.z); u.s[7]=f2bf(b.w);
  *(uint4*)(xb + i) = u.v;
}

__global__ __launch_bounds__(256) void k_conv_cb(const float* __restrict__ cb,
                                                 u16* __restrict__ cbb,
                                                 float* __restrict__ cnorm) {
  int k = blockIdx.x * 4 + (threadIdx.x >> 6);   // one wave per codebook row
  int lane = threadIdx.x & 63;
  size_t base = (size_t)k * DDIM + lane * 8;
  float4 a = *(const float4*)(cb + base);
  float4 b = *(const float4*)(cb + base + 4);
  union { u16 s[8]; uint4 v; } u;
  u.s[0]=f2bf(a.x); u.s[1]=f2bf(a.y); u.s[2]=f2bf(a.z); u.s[3]=f2bf(a.w);
  u.s[4]=f2bf(b.x); u.s[5]=f2bf(b.y); u.s[6]=f2bf(b.z); u.s[7]=f2bf(b.w);
  *(uint4*)(cbb + base) = u.v;
  float s = a.x*a.x + a.y*a.y + a.z*a.z + a.w*a.w
          + b.x*b.x + b.y*b.y + b.z*b.z + b.w*b.w;
  #pragma unroll
  for (int m = 1; m < 64; m <<= 1) s += __shfl_xor(s, m, 64);
  if (lane == 0) cnorm[k] = s;
}

// ---------------- GEMM + fused per-tile min/min2/argmin ----------------
// score[n][k] = cnorm[k] - 2 * dot(x_n, c_k)   (the ||x||^2 term is argmin-invariant)

__global__ __launch_bounds__(256) void k_gemm_min(
    const u16* __restrict__ Xbf, const u16* __restrict__ Cbf,
    const float* __restrict__ cnorm,
    float* __restrict__ mins, float* __restrict__ min2s,
    unsigned char* __restrict__ idxs)
{
  __shared__ __align__(16) u16 As[BM * BK];
  __shared__ __align__(16) u16 Bs[BN * BK];
  __shared__ float cnormLds[BN];
  __shared__ float eM1[2][BM];
  __shared__ float eM2[2][BM];
  __shared__ int   eIx[2][BM];

  int bid = blockIdx.x;
  // XCD-aware swizzle; 8192 % 8 == 0 so simple form is bijective
  int swz = ((bid & 7) << 10) | (bid >> 3);
  int mTile = swz >> 6;     // 0..127
  int nTile = swz & 63;     // 0..63
  int rowBase = mTile * BM;
  int colBase = nTile * BN;

  int tid = threadIdx.x;
  int lane = tid & 63;
  int wv = tid >> 6;
  int wr = wv >> 1;     // wave row (0..1)
  int wc = wv & 1;      // wave col (0..1)

  if (tid < BN) cnormLds[tid] = cnorm[colBase + tid];

  f32x4 acc[4][4];
  #pragma unroll
  for (int mi = 0; mi < 4; ++mi)
    #pragma unroll
    for (int ni = 0; ni < 4; ++ni)
      acc[mi][ni] = (f32x4){0.f, 0.f, 0.f, 0.f};

  for (int kt = 0; kt < NKT; ++kt) {
    if (kt) __syncthreads();
    // Stage A and B tiles: linear LDS dest, XOR-swizzled global SOURCE
    // (global_load_lds writes base + lane*16; swizzle must live in the source).
    #pragma unroll
    for (int i = 0; i < 4; ++i) {
      int f = wv * 64 + i * 256 + lane;   // flat 16B-chunk index
      int r = f >> 3;                     // tile row 0..127
      int p = f & 7;                      // chunk slot in row
      int gc = (p ^ (r & 7)) << 3;        // swizzled source element offset in row
      const u16* sa = Xbf + (size_t)(rowBase + r) * DDIM + kt * BK + gc;
      const u16* sb = Cbf + (size_t)(colBase + r) * DDIM + kt * BK + gc;
      gload16(sa, (void*)&As[(wv * 64 + i * 256) * 8]);
      gload16(sb, (void*)&Bs[(wv * 64 + i * 256) * 8]);
    }
    __syncthreads();
    #pragma unroll
    for (int ks = 0; ks < 2; ++ks) {
      bf16x8 aF[4], bF[4];
      #pragma unroll
      for (int mi = 0; mi < 4; ++mi) {
        int r = wr * 64 + mi * 16 + (lane & 15);
        int p = (ks * 4 + (lane >> 4)) ^ (r & 7);
        aF[mi] = *(const bf16x8*)&As[r * BK + p * 8];
      }
      #pragma unroll
      for (int ni = 0; ni < 4; ++ni) {
        int r = wc * 64 + ni * 16 + (lane & 15);
        int p = (ks * 4 + (lane >> 4)) ^ (r & 7);
        bF[ni] = *(const bf16x8*)&Bs[r * BK + p * 8];
      }
      #pragma unroll
      for (int mi = 0; mi < 4; ++mi)
        #pragma unroll
        for (int ni = 0; ni < 4; ++ni)
          acc[mi][ni] = __builtin_amdgcn_mfma_f32_16x16x32_bf16(aF[mi], bF[ni], acc[mi][ni], 0, 0, 0);
    }
  }

  // ---- epilogue: per-row (min, min2, argmin) over this block's 128 cols ----
  // C frag layout: col = lane&15, row = (lane>>4)*4 + reg  [m89-verified]
  float rm1[4][4], rm2[4][4]; int rix[4][4];
  #pragma unroll
  for (int mi = 0; mi < 4; ++mi) {
    #pragma unroll
    for (int j = 0; j < 4; ++j) {
      float a = 1e30f, b = 1e30f; int ii = 0;
      #pragma unroll
      for (int ni = 0; ni < 4; ++ni) {
        int c = wc * 64 + ni * 16 + (lane & 15);   // tile-local col 0..127
        float v = cnormLds[c] - 2.0f * acc[mi][ni][j];
        if (v < a || (v == a && c < ii)) { b = a; a = v; ii = c; }
        else if (v < b) b = v;
      }
      rm1[mi][j] = a; rm2[mi][j] = b; rix[mi][j] = ii;
    }
  }
  #pragma unroll
  for (int mask = 1; mask < 16; mask <<= 1) {
    #pragma unroll
    for (int mi = 0; mi < 4; ++mi)
      #pragma unroll
      for (int j = 0; j < 4; ++j) {
        float oa = __shfl_xor(rm1[mi][j], mask, 16);
        float ob = __shfl_xor(rm2[mi][j], mask, 16);
        int   oi = __shfl_xor(rix[mi][j], mask, 16);
        combine(rm1[mi][j], rm2[mi][j], rix[mi][j], oa, ob, oi);
      }
  }
  if ((lane & 15) == 0) {
    int q4 = lane >> 4;
    #pragma unroll
    for (int mi = 0; mi < 4; ++mi)
      #pragma unroll
      for (int j = 0; j < 4; ++j) {
        int r = wr * 64 + mi * 16 + q4 * 4 + j;
        eM1[wc][r] = rm1[mi][j];
        eM2[wc][r] = rm2[mi][j];
        eIx[wc][r] = rix[mi][j];
      }
  }
  __syncthreads();
  if (tid < BM) {
    int r = tid;
    float a0 = eM1[0][r], b0 = eM2[0][r]; int i0 = eIx[0][r];
    combine(a0, b0, i0, eM1[1][r], eM2[1][r], eIx[1][r]);
    size_t o = (size_t)(rowBase + r) * NTILES + nTile;
    mins[o]  = a0;
    min2s[o] = b0;
    idxs[o]  = (unsigned char)i0;
  }
}

// ---------------- fp64 refinement (one wave per row) ----------------

__global__ __launch_bounds__(256) void k_refine(
    const float* __restrict__ x, const float* __restrict__ cb,
    const float* __restrict__ cnorm, const float* __restrict__ mins,
    const float* __restrict__ min2s, const unsigned char* __restrict__ idxs,
    unsigned int* __restrict__ bestOut)
{
  int n = blockIdx.x * 4 + (threadIdx.x >> 6);
  int lane = threadIdx.x & 63;
  size_t tb = (size_t)n * NTILES;
  float tm  = mins[tb + lane];
  float tm2 = min2s[tb + lane];
  int   til = idxs[tb + lane];
  float g = tm;
  #pragma unroll
  for (int m = 1; m < 64; m <<= 1) g = fminf(g, __shfl_xor(g, m, 64));
  float T = g + MARGIN;
  unsigned long long q = __ballot(tm <= T);
  const float* xr = x + (size_t)n * DDIM;
  float4 xa = *(const float4*)(xr + lane * 8);
  float4 xb = *(const float4*)(xr + lane * 8 + 4);

  double best = 1e300;
  int bi = 0x7fffffff;

  while (q) {
    int t = __ffsll(q) - 1;
    q &= q - 1;
    int cidx  = __shfl(til, t, 64);
    float m2v = __shfl(tm2, t, 64);
    int col = t * BN + cidx;
    {
      const float* cr = cb + (size_t)col * DDIM + lane * 8;
      float4 ca = *(const float4*)cr;
      float4 cv = *(const float4*)(cr + 4);
      double s = 0.0, d;
      d = (double)xa.x - (double)ca.x; s += d*d;
      d = (double)xa.y - (double)ca.y; s += d*d;
      d = (double)xa.z - (double)ca.z; s += d*d;
      d = (double)xa.w - (double)ca.w; s += d*d;
      d = (double)xb.x - (double)cv.x; s += d*d;
      d = (double)xb.y - (double)cv.y; s += d*d;
      d = (double)xb.z - (double)cv.z; s += d*d;
      d = (double)xb.w - (double)cv.w; s += d*d;
      #pragma unroll
      for (int m = 1; m < 64; m <<= 1) s += shfl_xor_dbl(s, m);
      if (s < best || (s == best && col < bi)) { best = s; bi = col; }
    }
    if (m2v <= T) {
      // rare: another col of this tile may be within margin -> rescan the tile
      for (int c2 = 0; c2 < BN; ++c2) {
        int col2 = t * BN + c2;
        if (col2 == col) continue;
        const float* cr = cb + (size_t)col2 * DDIM + lane * 8;
        float4 ca = *(const float4*)cr;
        float4 cv = *(const float4*)(cr + 4);
        float p = xa.x*ca.x + xa.y*ca.y + xa.z*ca.z + xa.w*ca.w
                + xb.x*cv.x + xb.y*cv.y + xb.z*cv.z + xb.w*cv.w;
        #pragma unroll
        for (int m = 1; m < 64; m <<= 1) p += __shfl_xor(p, m, 64);
        float s32 = cnorm[col2] - 2.0f * p;
        if (s32 <= T) {
          double s = 0.0, dd;
          dd = (double)xa.x - (double)ca.x; s += dd*dd;
          dd = (double)xa.y - (double)ca.y; s += dd*dd;
          dd = (double)xa.z - (double)ca.z; s += dd*dd;
          dd = (double)xa.w - (double)ca.w; s += dd*dd;
          dd = (double)xb.x - (double)cv.x; s += dd*dd;
          dd = (double)xb.y - (double)cv.y; s += dd*dd;
          dd = (double)xb.z - (double)cv.z; s += dd*dd;
          dd = (double)xb.w - (double)cv.w; s += dd*dd;
          #pragma unroll
          for (int m = 1; m < 64; m <<= 1) s += shfl_xor_dbl(s, m);
          if (s < best || (s == best && col2 < bi)) { best = s; bi = col2; }
        }
      }
    }
  }
  if (lane == 0) bestOut[n] = (unsigned int)bi;
}

// ---------------- gather ----------------

__global__ __launch_bounds__(256) void k_gather(const float* __restrict__ cb,
                                                const unsigned int* __restrict__ bestIdx,
                                                float* __restrict__ out) {
  int n = blockIdx.x * 4 + (threadIdx.x >> 6);
  int lane = threadIdx.x & 63;
  unsigned int b = bestIdx[n];
  const float4* s = (const float4*)(cb + (size_t)b * DDIM);
  float4* dp = (float4*)(out + (size_t)n * DDIM);
  dp[lane * 2]     = s[lane * 2];
  dp[lane * 2 + 1] = s[lane * 2 + 1];
}

// ---------------- launch ----------------

extern "C" void kernel_launch(void* const* d_in, const int* in_sizes, int n_in,
                              void* d_out, int out_size, void* d_ws, size_t ws_size,
                              hipStream_t stream) {
  const float* x  = (const float*)d_in[0];   // [16384, 512]
  const float* cb = (const float*)d_in[1];   // [8192, 512]
  float* out = (float*)d_out;

  // d_out doubles as scratch until the final gather (exactly 32 MiB):
  //   [0,16M)   Xbf bf16,  [16M,24M) Cbf bf16,  [24M,28M) mins f32,  [28M,32M) min2 f32
  char* ob = (char*)d_out;
  u16*   Xbf   = (u16*)ob;
  u16*   Cbf   = (u16*)(ob + 16ull * 1024 * 1024);
  float* mins  = (float*)(ob + 24ull * 1024 * 1024);
  float* min2s = (float*)(ob + 28ull * 1024 * 1024);

  // ws: cnorm 32KB | tile argmin bytes 1MB | bestIdx 64KB  (~1.13 MiB)
  char* wsb = (char*)d_ws;
  float* cnorm = (float*)wsb;
  unsigned char* idxs = (unsigned char*)(wsb + 32 * 1024);
  unsigned int* bestIdx = (unsigned int*)(wsb + 32 * 1024 + 1024 * 1024);

  k_conv_x  <<<4096, 256, 0, stream>>>(x, Xbf);
  k_conv_cb <<<2048, 256, 0, stream>>>(cb, Cbf, cnorm);
  k_gemm_min<<<8192, 256, 0, stream>>>(Xbf, Cbf, cnorm, mins, min2s, idxs);
  k_refine  <<<4096, 256, 0, stream>>>(x, cb, cnorm, mins, min2s, idxs, bestIdx);
  k_gather  <<<4096, 256, 0, stream>>>(cb, bestIdx, out);
}

// Round 3
// 387.499 us; speedup vs baseline: 1.2052x; 1.2052x over previous
//
#include <hip/hip_runtime.h>

// x [16384,512] f32, codebook [8192,512] f32 -> out[n] = codebook[argmin_k ||x_n-c_k||^2]
// bf16 MFMA GEMM (2-phase double-buffered pipeline) computing score = cnorm - 2 x.c,
// fused per-(row,128-col-tile) top-3 stats via sortable keys, then guaranteed-inclusive
// fp64 refinement + gather.

#define MROWS 16384
#define KCB   8192
#define DDIM  512
#define BM 128
#define BN 128
#define BK 64
#define NKT (DDIM / BK)      // 8 K-steps
#define NTILES (KCB / BN)    // 64 column tiles
#define MARGIN 8.0f          // > 2*worst-case bf16 score err (~6.4) + quantize slop

typedef unsigned short u16;
typedef unsigned int uint;
typedef __attribute__((ext_vector_type(8))) short bf16x8;
typedef __attribute__((ext_vector_type(4))) float f32x4;

__device__ inline u16 f2bf(float f) {
  unsigned int u = __float_as_uint(f);
  u += 0x7FFFu + ((u >> 16) & 1u);
  return (u16)(u >> 16);
}

__device__ inline void gload16(const void* g, void* l) {
  __builtin_amdgcn_global_load_lds((const __attribute__((address_space(1))) void*)g,
                                   (__attribute__((address_space(3))) void*)l,
                                   16, 0, 0);
}

__device__ inline double shfl_xor_dbl(double v, int m) {
  long long l = __double_as_longlong(v);
  int lo = (int)(l & 0xffffffffLL), hi = (int)(l >> 32);
  lo = __shfl_xor(lo, m, 64);
  hi = __shfl_xor(hi, m, 64);
  return __longlong_as_double(((long long)hi << 32) | (unsigned long long)(unsigned int)lo);
}

// decode sortable key (low 7 bits = col) to a conservative-low float value
__device__ inline float keyval(uint k) {
  uint u = k & 0xFFFFFF80u;
  uint bits = (u & 0x80000000u) ? (u & 0x7FFFFFFFu) : ~u;
  return __uint_as_float(bits);
}

// ---------------- conversion kernels ----------------

__global__ __launch_bounds__(256) void k_conv_x(const float* __restrict__ x,
                                                u16* __restrict__ xb) {
  size_t i = ((size_t)blockIdx.x * 256 + threadIdx.x) * 8;
  float4 a = *(const float4*)(x + i);
  float4 b = *(const float4*)(x + i + 4);
  union { u16 s[8]; uint4 v; } u;
  u.s[0]=f2bf(a.x); u.s[1]=f2bf(a.y); u.s[2]=f2bf(a.z); u.s[3]=f2bf(a.w);
  u.s[4]=f2bf(b.x); u.s[5]=f2bf(b.y); u.s[6]=f2bf(b.z); u.s[7]=f2bf(b.w);
  *(uint4*)(xb + i) = u.v;
}

__global__ __launch_bounds__(256) void k_conv_cb(const float* __restrict__ cb,
                                                 u16* __restrict__ cbb,
                                                 float* __restrict__ cnorm) {
  int k = blockIdx.x * 4 + (threadIdx.x >> 6);
  int lane = threadIdx.x & 63;
  size_t base = (size_t)k * DDIM + lane * 8;
  float4 a = *(const float4*)(cb + base);
  float4 b = *(const float4*)(cb + base + 4);
  union { u16 s[8]; uint4 v; } u;
  u.s[0]=f2bf(a.x); u.s[1]=f2bf(a.y); u.s[2]=f2bf(a.z); u.s[3]=f2bf(a.w);
  u.s[4]=f2bf(b.x); u.s[5]=f2bf(b.y); u.s[6]=f2bf(b.z); u.s[7]=f2bf(b.w);
  *(uint4*)(cbb + base) = u.v;
  float s = a.x*a.x + a.y*a.y + a.z*a.z + a.w*a.w
          + b.x*b.x + b.y*b.y + b.z*b.z + b.w*b.w;
  #pragma unroll
  for (int m = 1; m < 64; m <<= 1) s += __shfl_xor(s, m, 64);
  if (lane == 0) cnorm[k] = s;
}

// ---------------- GEMM + fused per-tile top-3 ----------------

__global__ __launch_bounds__(256) void k_gemm_min(
    const u16* __restrict__ Xbf, const u16* __restrict__ Cbf,
    const float* __restrict__ cnorm, uint2* __restrict__ stats)
{
  __shared__ __align__(16) u16 As[2][BM * BK];   // 2 x 16 KB
  __shared__ __align__(16) u16 Bs[2][BN * BK];   // 2 x 16 KB  (total 64 KB)

  int bid = blockIdx.x;
  // XCD panel-resident walk: XCD x owns mTiles [16x,16x+16), streams nTiles once.
  int xcd = bid & 7;
  int j   = bid >> 3;                 // 0..1023
  int mTile = xcd * 16 + (j & 15);    // 0..127
  int nTile = j >> 4;                 // 0..63
  int rowBase = mTile * BM;
  int colBase = nTile * BN;

  int tid = threadIdx.x;
  int lane = tid & 63;
  int wv = tid >> 6;
  int wr = wv >> 1;
  int wc = wv & 1;
  int grp = lane >> 4;    // 0..3
  int l15 = lane & 15;

  // staging source pointers (swizzled global source, linear LDS dest)
  const u16* srcA[4]; const u16* srcB[4];
  #pragma unroll
  for (int i = 0; i < 4; ++i) {
    int f = wv * 64 + i * 256 + lane;   // flat 16B-chunk index 0..2047
    int r = f >> 3;
    int p = f & 7;
    int gc = (p ^ (r & 7)) << 3;
    srcA[i] = Xbf + (size_t)(rowBase + r) * DDIM + gc;
    srcB[i] = Cbf + (size_t)(colBase + r) * DDIM + gc;
  }

  // fragment LDS element offsets (kt-invariant)
  int offA[4][2], offB[4][2];
  #pragma unroll
  for (int mi = 0; mi < 4; ++mi) {
    int rA = wr * 64 + mi * 16 + l15;
    int rB = wc * 64 + mi * 16 + l15;
    #pragma unroll
    for (int ks = 0; ks < 2; ++ks) {
      offA[mi][ks] = rA * BK + (((ks * 4 + grp) ^ (rA & 7)) << 3);
      offB[mi][ks] = rB * BK + (((ks * 4 + grp) ^ (rB & 7)) << 3);
    }
  }

  f32x4 acc[4][4];
  #pragma unroll
  for (int mi = 0; mi < 4; ++mi)
    #pragma unroll
    for (int ni = 0; ni < 4; ++ni)
      acc[mi][ni] = (f32x4){0.f, 0.f, 0.f, 0.f};

#define STAGE(buf_, kt_)                                                      \
  {                                                                           \
    _Pragma("unroll")                                                         \
    for (int i = 0; i < 4; ++i) {                                             \
      gload16(srcA[i] + (kt_) * BK, (void*)&As[buf_][(wv * 64 + i * 256) * 8]); \
      gload16(srcB[i] + (kt_) * BK, (void*)&Bs[buf_][(wv * 64 + i * 256) * 8]); \
    }                                                                         \
  }

  int cur = 0;
  STAGE(0, 0);
  __syncthreads();                       // drain vmcnt -> buf0 ready
  for (int kt = 0; kt < NKT; ++kt) {
    if (kt + 1 < NKT) STAGE(cur ^ 1, kt + 1);   // prefetch next tile (overlaps compute)
    const u16* As_c = &As[cur][0];
    const u16* Bs_c = &Bs[cur][0];
    #pragma unroll
    for (int ks = 0; ks < 2; ++ks) {
      bf16x8 aF[4], bF[4];
      #pragma unroll
      for (int mi = 0; mi < 4; ++mi) aF[mi] = *(const bf16x8*)&As_c[offA[mi][ks]];
      #pragma unroll
      for (int ni = 0; ni < 4; ++ni) bF[ni] = *(const bf16x8*)&Bs_c[offB[ni][ks]];
      #pragma unroll
      for (int mi = 0; mi < 4; ++mi)
        #pragma unroll
        for (int ni = 0; ni < 4; ++ni)
          acc[mi][ni] = __builtin_amdgcn_mfma_f32_16x16x32_bf16(aF[mi], bF[ni], acc[mi][ni], 0, 0, 0);
    }
    __syncthreads();                     // drains prefetch vmcnt AFTER compute
    cur ^= 1;
  }

  // ---- epilogue: per-row top-3 over this block's 128 cols via sortable keys ----
  // C frag layout: col = lane&15, row = (lane>>4)*4 + reg  [m89-verified]
  float* scC = (float*)(&As[0][0]);          // reuse LDS (all As reads done)
  uint*  scK = (uint*)(scC + 128);           // [2][128][3] triples
  if (tid < BN) scC[tid] = cnorm[colBase + tid];
  __syncthreads();

  #pragma unroll
  for (int mi = 0; mi < 4; ++mi) {
    #pragma unroll
    for (int jj = 0; jj < 4; ++jj) {
      uint kk[4];
      #pragma unroll
      for (int ni = 0; ni < 4; ++ni) {
        int c = wc * 64 + ni * 16 + l15;
        float v = scC[c] - 2.0f * acc[mi][ni][jj];
        uint u = __float_as_uint(v);
        u = ((int)u < 0) ? ~u : (u | 0x80000000u);
        kk[ni] = (u & 0xFFFFFF80u) | (uint)c;
      }
      uint lm = min(min(kk[0], kk[1]), min(kk[2], kk[3]));
      #pragma unroll
      for (int m = 1; m < 16; m <<= 1) lm = min(lm, (uint)__shfl_xor((int)lm, m, 16));
      uint k1 = lm;
      #pragma unroll
      for (int ni = 0; ni < 4; ++ni) if (kk[ni] == k1) kk[ni] = 0xFFFFFFFFu;
      lm = min(min(kk[0], kk[1]), min(kk[2], kk[3]));
      #pragma unroll
      for (int m = 1; m < 16; m <<= 1) lm = min(lm, (uint)__shfl_xor((int)lm, m, 16));
      uint k2 = lm;
      #pragma unroll
      for (int ni = 0; ni < 4; ++ni) if (kk[ni] == k2) kk[ni] = 0xFFFFFFFFu;
      lm = min(min(kk[0], kk[1]), min(kk[2], kk[3]));
      #pragma unroll
      for (int m = 1; m < 16; m <<= 1) lm = min(lm, (uint)__shfl_xor((int)lm, m, 16));
      uint k3 = lm;
      if (l15 == 0) {
        int r = wr * 64 + mi * 16 + grp * 4 + jj;
        uint* p = &scK[(wc * 128 + r) * 3];
        p[0] = k1; p[1] = k2; p[2] = k3;
      }
    }
  }
  __syncthreads();
  if (tid < BM) {
    int r = tid;
    uint a1 = scK[r * 3], a2 = scK[r * 3 + 1], a3 = scK[r * 3 + 2];
    const uint* q = &scK[(128 + r) * 3];
    #pragma unroll
    for (int z = 0; z < 3; ++z) {
      uint k = q[z];
      bool lt1 = k < a1, lt2 = k < a2, lt3 = k < a3;
      a3 = lt3 ? (lt2 ? a2 : k) : a3;
      a2 = lt2 ? (lt1 ? a1 : k) : a2;
      a1 = lt1 ? k : a1;
    }
    float v1 = keyval(a1), v2 = keyval(a2), v3 = keyval(a3);
    uint i1 = a1 & 127u, i2 = a2 & 127u;
    uint d2 = min(255u, (uint)((v2 - v1) * 4.0f));   // floor -> conservative-low m2'
    uint d3 = min(255u, (uint)((v3 - v1) * 4.0f));
    uint2 st;
    st.x = __float_as_uint(v1);
    st.y = i1 | (i2 << 7) | (d2 << 14) | (d3 << 22);
    stats[(size_t)(rowBase + r) * NTILES + nTile] = st;
  }
#undef STAGE
}

// ---------------- fp64 refinement (one wave per row) ----------------

__device__ inline void eval64(const float4& xa, const float4& xb,
                              const float* __restrict__ cb, int col,
                              double& best, int& bi, int lane) {
  const float* cr = cb + (size_t)col * DDIM + lane * 8;
  float4 ca = *(const float4*)cr;
  float4 cv = *(const float4*)(cr + 4);
  double s = 0.0, d;
  d = (double)xa.x - (double)ca.x; s += d*d;
  d = (double)xa.y - (double)ca.y; s += d*d;
  d = (double)xa.z - (double)ca.z; s += d*d;
  d = (double)xa.w - (double)ca.w; s += d*d;
  d = (double)xb.x - (double)cv.x; s += d*d;
  d = (double)xb.y - (double)cv.y; s += d*d;
  d = (double)xb.z - (double)cv.z; s += d*d;
  d = (double)xb.w - (double)cv.w; s += d*d;
  #pragma unroll
  for (int m = 1; m < 64; m <<= 1) s += shfl_xor_dbl(s, m);
  if (s < best || (s == best && col < bi)) { best = s; bi = col; }
}

__global__ __launch_bounds__(256) void k_refine(
    const float* __restrict__ x, const float* __restrict__ cb,
    const float* __restrict__ cnorm, const uint2* __restrict__ stats,
    unsigned int* __restrict__ bestOut)
{
  int n = blockIdx.x * 4 + (threadIdx.x >> 6);
  int lane = threadIdx.x & 63;
  uint2 st = stats[(size_t)n * NTILES + lane];   // lane t owns tile t
  float m1 = __uint_as_float(st.x);
  int   i1 = st.y & 127, i2 = (st.y >> 7) & 127;
  float m2 = m1 + ((st.y >> 14) & 255u) * 0.25f;
  float m3 = m1 + ((st.y >> 22) & 255u) * 0.25f;
  float g = m1;
  #pragma unroll
  for (int m = 1; m < 64; m <<= 1) g = fminf(g, __shfl_xor(g, m, 64));
  float T = g + MARGIN;
  unsigned long long q1 = __ballot(m1 <= T);
  unsigned long long q2 = __ballot(m2 <= T);
  unsigned long long qr = __ballot(m3 <= T);

  const float* xr = x + (size_t)n * DDIM;
  float4 xa = *(const float4*)(xr + lane * 8);
  float4 xb = *(const float4*)(xr + lane * 8 + 4);

  double best = 1e300;
  int bi = 0x7fffffff;

  while (q1) {
    int t = __ffsll(q1) - 1; q1 &= q1 - 1;
    int col = t * BN + __shfl(i1, t, 64);
    eval64(xa, xb, cb, col, best, bi, lane);
  }
  while (q2) {
    int t = __ffsll(q2) - 1; q2 &= q2 - 1;
    int col = t * BN + __shfl(i2, t, 64);
    eval64(xa, xb, cb, col, best, bi, lane);
  }
  while (qr) {
    int t = __ffsll(qr) - 1; qr &= qr - 1;
    for (int c2 = 0; c2 < BN; ++c2) {
      int col2 = t * BN + c2;
      const float* cr = cb + (size_t)col2 * DDIM + lane * 8;
      float4 ca = *(const float4*)cr;
      float4 cv = *(const float4*)(cr + 4);
      float p = xa.x*ca.x + xa.y*ca.y + xa.z*ca.z + xa.w*ca.w
              + xb.x*cv.x + xb.y*cv.y + xb.z*cv.z + xb.w*cv.w;
      #pragma unroll
      for (int m = 1; m < 64; m <<= 1) p += __shfl_xor(p, m, 64);
      float s32 = cnorm[col2] - 2.0f * p;
      if (s32 <= T) {
        double s = 0.0, dd;
        dd = (double)xa.x - (double)ca.x; s += dd*dd;
        dd = (double)xa.y - (double)ca.y; s += dd*dd;
        dd = (double)xa.z - (double)ca.z; s += dd*dd;
        dd = (double)xa.w - (double)ca.w; s += dd*dd;
        dd = (double)xb.x - (double)cv.x; s += dd*dd;
        dd = (double)xb.y - (double)cv.y; s += dd*dd;
        dd = (double)xb.z - (double)cv.z; s += dd*dd;
        dd = (double)xb.w - (double)cv.w; s += dd*dd;
        #pragma unroll
        for (int m = 1; m < 64; m <<= 1) s += shfl_xor_dbl(s, m);
        if (s < best || (s == best && col2 < bi)) { best = s; bi = col2; }
      }
    }
  }
  if (lane == 0) bestOut[n] = (unsigned int)bi;
}

// ---------------- gather ----------------

__global__ __launch_bounds__(256) void k_gather(const float* __restrict__ cb,
                                                const unsigned int* __restrict__ bestIdx,
                                                float* __restrict__ out) {
  int n = blockIdx.x * 4 + (threadIdx.x >> 6);
  int lane = threadIdx.x & 63;
  unsigned int b = bestIdx[n];
  const float4* s = (const float4*)(cb + (size_t)b * DDIM);
  float4* dp = (float4*)(out + (size_t)n * DDIM);
  dp[lane * 2]     = s[lane * 2];
  dp[lane * 2 + 1] = s[lane * 2 + 1];
}

// ---------------- launch ----------------

extern "C" void kernel_launch(void* const* d_in, const int* in_sizes, int n_in,
                              void* d_out, int out_size, void* d_ws, size_t ws_size,
                              hipStream_t stream) {
  const float* x  = (const float*)d_in[0];   // [16384, 512]
  const float* cb = (const float*)d_in[1];   // [8192, 512]
  float* out = (float*)d_out;

  // d_out doubles as scratch until the final gather (exactly 32 MiB):
  //   [0,16M) Xbf bf16, [16M,24M) Cbf bf16, [24M,32M) stats uint2 [16384][64]
  char* ob = (char*)d_out;
  u16*   Xbf   = (u16*)ob;
  u16*   Cbf   = (u16*)(ob + 16ull * 1024 * 1024);
  uint2* stats = (uint2*)(ob + 24ull * 1024 * 1024);

  // ws: cnorm 32KB | bestIdx 64KB
  char* wsb = (char*)d_ws;
  float* cnorm = (float*)wsb;
  unsigned int* bestIdx = (unsigned int*)(wsb + 32 * 1024);

  k_conv_x  <<<4096, 256, 0, stream>>>(x, Xbf);
  k_conv_cb <<<2048, 256, 0, stream>>>(cb, Cbf, cnorm);
  k_gemm_min<<<8192, 256, 0, stream>>>(Xbf, Cbf, cnorm, stats);
  k_refine  <<<4096, 256, 0, stream>>>(x, cb, cnorm, stats, bestIdx);
  k_gather  <<<4096, 256, 0, stream>>>(cb, bestIdx, out);
}

// Round 5
// 342.599 us; speedup vs baseline: 1.3631x; 1.1311x over previous
//
#include <hip/hip_runtime.h>

// x [16384,512] f32, codebook [8192,512] f32 -> out[n] = codebook[argmin_k ||x_n-c_k||^2]
// 256x256 bf16 MFMA GEMM, 2-deep pipelined (1 barrier per K-tile), fused per-(row,128col)
// top-3 stats; guaranteed-inclusive fp64 refinement; gather.

#define MROWS 16384
#define KCB   8192
#define DDIM  512
#define BM 256
#define BN 256
#define BK 64
#define NKT (DDIM / BK)      // 8 K-tiles
#define NTILES (KCB / 128)   // 64 stat tiles of 128 cols
#define MARGIN 8.0f

typedef unsigned short u16;
typedef unsigned int uint;
typedef __attribute__((ext_vector_type(8))) short bf16x8;
typedef __attribute__((ext_vector_type(4))) float f32x4;

__device__ inline u16 f2bf(float f) {
  unsigned int u = __float_as_uint(f);
  u += 0x7FFFu + ((u >> 16) & 1u);
  return (u16)(u >> 16);
}

__device__ inline void gload16(const void* g, void* l) {
  __builtin_amdgcn_global_load_lds((const __attribute__((address_space(1))) void*)g,
                                   (__attribute__((address_space(3))) void*)l,
                                   16, 0, 0);
}

__device__ inline double shfl_xor_dbl(double v, int m) {
  long long l = __double_as_longlong(v);
  int lo = (int)(l & 0xffffffffLL), hi = (int)(l >> 32);
  lo = __shfl_xor(lo, m, 64);
  hi = __shfl_xor(hi, m, 64);
  return __longlong_as_double(((long long)hi << 32) | (unsigned long long)(unsigned int)lo);
}

__device__ inline float keyval(uint k) {
  uint u = k & 0xFFFFFF80u;
  uint bits = (u & 0x80000000u) ? (u & 0x7FFFFFFFu) : ~u;
  return __uint_as_float(bits);
}

// ---------------- conversion kernels ----------------

__global__ __launch_bounds__(256) void k_conv_x(const float* __restrict__ x,
                                                u16* __restrict__ xb) {
  size_t i = ((size_t)blockIdx.x * 256 + threadIdx.x) * 8;
  float4 a = *(const float4*)(x + i);
  float4 b = *(const float4*)(x + i + 4);
  union { u16 s[8]; uint4 v; } u;
  u.s[0]=f2bf(a.x); u.s[1]=f2bf(a.y); u.s[2]=f2bf(a.z); u.s[3]=f2bf(a.w);
  u.s[4]=f2bf(b.x); u.s[5]=f2bf(b.y); u.s[6]=f2bf(b.z); u.s[7]=f2bf(b.w);
  *(uint4*)(xb + i) = u.v;
}

__global__ __launch_bounds__(256) void k_conv_cb(const float* __restrict__ cb,
                                                 u16* __restrict__ cbb,
                                                 float* __restrict__ cnorm) {
  int k = blockIdx.x * 4 + (threadIdx.x >> 6);
  int lane = threadIdx.x & 63;
  size_t base = (size_t)k * DDIM + lane * 8;
  float4 a = *(const float4*)(cb + base);
  float4 b = *(const float4*)(cb + base + 4);
  union { u16 s[8]; uint4 v; } u;
  u.s[0]=f2bf(a.x); u.s[1]=f2bf(a.y); u.s[2]=f2bf(a.z); u.s[3]=f2bf(a.w);
  u.s[4]=f2bf(b.x); u.s[5]=f2bf(b.y); u.s[6]=f2bf(b.z); u.s[7]=f2bf(b.w);
  *(uint4*)(cbb + base) = u.v;
  float s = a.x*a.x + a.y*a.y + a.z*a.z + a.w*a.w
          + b.x*b.x + b.y*b.y + b.z*b.z + b.w*b.w;
  #pragma unroll
  for (int m = 1; m < 64; m <<= 1) s += __shfl_xor(s, m, 64);
  if (lane == 0) cnorm[k] = s;
}

// ---------------- 256x256 GEMM + fused per-tile top-3 ----------------

__global__ __launch_bounds__(512, 2) void k_gemm_min(
    const u16* __restrict__ Xbf, const u16* __restrict__ Cbf,
    const float* __restrict__ cnorm, uint2* __restrict__ stats)
{
  extern __shared__ u16 lds[];   // [0,32K) A0 | [32K,64K) A1 | [64K,96K) B0 | [96K,128K) B1

  int bid = blockIdx.x;          // 2048 blocks
  int xcd = bid & 7;
  int j   = bid >> 3;            // 0..255
  int mTile = xcd * 8 + (j & 7); // 0..63
  int nTile = j >> 3;            // 0..31
  int rowBase = mTile * BM;
  int colBase = nTile * BN;

  int tid = threadIdx.x;
  int lane = tid & 63;
  int wv = tid >> 6;     // 0..7
  int wr = wv >> 2;      // 0..1  (M half)
  int wc = wv & 3;       // 0..3  (N quarter)
  int grp = lane >> 4;
  int l15 = lane & 15;

  // staging sources: XOR-swizzled global source, linear LDS dest
  const u16 *srcA[4], *srcB[4];
  #pragma unroll
  for (int i = 0; i < 4; ++i) {
    int f = i * 512 + tid;        // chunk 0..2047
    int r = f >> 3;               // tile row 0..255
    int p = f & 7;
    int gc = (p ^ (r & 7)) << 3;
    srcA[i] = Xbf + (size_t)(rowBase + r) * DDIM + gc;
    srcB[i] = Cbf + (size_t)(colBase + r) * DDIM + gc;
  }

  // cnorm for this wave's 64 cols, kept in registers
  float cnormReg[4];
  #pragma unroll
  for (int ni = 0; ni < 4; ++ni)
    cnormReg[ni] = cnorm[colBase + wc * 64 + ni * 16 + l15];

  f32x4 acc[8][4];
  #pragma unroll
  for (int mi = 0; mi < 8; ++mi)
    #pragma unroll
    for (int ni = 0; ni < 4; ++ni)
      acc[mi][ni] = (f32x4){0.f, 0.f, 0.f, 0.f};

#define STAGE(cur_, kt_)                                                     \
  {                                                                          \
    u16* Ad = lds + (cur_) * 16384;                                          \
    u16* Bd = lds + 32768 + (cur_) * 16384;                                  \
    _Pragma("unroll")                                                        \
    for (int i = 0; i < 4; ++i) {                                            \
      gload16(srcA[i] + (kt_) * BK, (void*)(Ad + (i * 512 + wv * 64) * 8));  \
      gload16(srcB[i] + (kt_) * BK, (void*)(Bd + (i * 512 + wv * 64) * 8));  \
    }                                                                        \
  }

  STAGE(0, 0);
  STAGE(1, 1);
  __syncthreads();                 // prologue drain (only exposed latency)

  int cur = 0;
  for (int kt = 0; kt < NKT; ++kt) {
    const u16* Ab = lds + cur * 16384;
    const u16* Bb = lds + 32768 + cur * 16384;
    #pragma unroll
    for (int ks = 0; ks < 2; ++ks) {
      bf16x8 bF[4];
      #pragma unroll
      for (int ni = 0; ni < 4; ++ni) {
        int rB = wc * 64 + ni * 16 + l15;
        bF[ni] = *(const bf16x8*)&Bb[rB * BK + (((ks * 4 + grp) ^ (rB & 7)) << 3)];
      }
      #pragma unroll
      for (int mi = 0; mi < 8; ++mi) {
        int rA = wr * 128 + mi * 16 + l15;
        bf16x8 aF = *(const bf16x8*)&Ab[rA * BK + (((ks * 4 + grp) ^ (rA & 7)) << 3)];
        #pragma unroll
        for (int ni = 0; ni < 4; ++ni)
          acc[mi][ni] = __builtin_amdgcn_mfma_f32_16x16x32_bf16(aF, bF[ni], acc[mi][ni], 0, 0, 0);
      }
    }
    __syncthreads();               // frees buf[cur]; drains loads issued LAST iter (latency hidden)
    if (kt + 2 < NKT) STAGE(cur, kt + 2);
    cur ^= 1;
  }
#undef STAGE

  // ---- epilogue: per-row top-3 over each 128-col stat tile ----
  // C frag: col = lane&15, row = (lane>>4)*4 + reg
  uint* scK = (uint*)lds;          // [8 waves][128 rows][3] triples (12 KB)
  #pragma unroll
  for (int mi = 0; mi < 8; ++mi) {
    #pragma unroll
    for (int jj = 0; jj < 4; ++jj) {
      uint kk[4];
      #pragma unroll
      for (int ni = 0; ni < 4; ++ni) {
        int cl = (wc & 1) * 64 + ni * 16 + l15;   // stat-tile-local col 0..127
        float v = cnormReg[ni] - 2.0f * acc[mi][ni][jj];
        uint u = __float_as_uint(v);
        u = ((int)u < 0) ? ~u : (u | 0x80000000u);
        kk[ni] = (u & 0xFFFFFF80u) | (uint)cl;
      }
      uint lm = min(min(kk[0], kk[1]), min(kk[2], kk[3]));
      #pragma unroll
      for (int m = 1; m < 16; m <<= 1) lm = min(lm, (uint)__shfl_xor((int)lm, m, 16));
      uint k1 = lm;
      #pragma unroll
      for (int ni = 0; ni < 4; ++ni) if (kk[ni] == k1) kk[ni] = 0xFFFFFFFFu;
      lm = min(min(kk[0], kk[1]), min(kk[2], kk[3]));
      #pragma unroll
      for (int m = 1; m < 16; m <<= 1) lm = min(lm, (uint)__shfl_xor((int)lm, m, 16));
      uint k2 = lm;
      #pragma unroll
      for (int ni = 0; ni < 4; ++ni) if (kk[ni] == k2) kk[ni] = 0xFFFFFFFFu;
      lm = min(min(kk[0], kk[1]), min(kk[2], kk[3]));
      #pragma unroll
      for (int m = 1; m < 16; m <<= 1) lm = min(lm, (uint)__shfl_xor((int)lm, m, 16));
      uint k3 = lm;
      if (l15 == 0) {
        int rr = mi * 16 + grp * 4 + jj;          // wave-local row 0..127
        uint* p = &scK[(wv * 128 + rr) * 3];
        p[0] = k1; p[1] = k2; p[2] = k3;
      }
    }
  }
  __syncthreads();
  {
    int r = tid >> 1;              // block row 0..255
    int s = tid & 1;               // stat tile within block
    int wa = (r >> 7) * 4 + s * 2;
    int rr = r & 127;
    const uint* pa = &scK[(wa * 128 + rr) * 3];
    const uint* pb = &scK[((wa + 1) * 128 + rr) * 3];
    uint a1 = pa[0], a2 = pa[1], a3 = pa[2];
    #pragma unroll
    for (int z = 0; z < 3; ++z) {
      uint k = pb[z];
      bool lt1 = k < a1, lt2 = k < a2, lt3 = k < a3;
      a3 = lt3 ? (lt2 ? a2 : k) : a3;
      a2 = lt2 ? (lt1 ? a1 : k) : a2;
      a1 = lt1 ? k : a1;
    }
    float v1 = keyval(a1), v2 = keyval(a2), v3 = keyval(a3);
    uint i1 = a1 & 127u, i2 = a2 & 127u;
    uint d2 = min(255u, (uint)((v2 - v1) * 4.0f));   // floor -> conservative-low
    uint d3 = min(255u, (uint)((v3 - v1) * 4.0f));
    uint2 st;
    st.x = __float_as_uint(v1);
    st.y = i1 | (i2 << 7) | (d2 << 14) | (d3 << 22);
    stats[(size_t)(rowBase + r) * NTILES + nTile * 2 + s] = st;
  }
}

// ---------------- fp64 refinement (one wave per row) ----------------

__device__ inline void eval64(const float4& xa, const float4& xb,
                              const float* __restrict__ cb, int col,
                              double& best, int& bi, int lane) {
  const float* cr = cb + (size_t)col * DDIM + lane * 8;
  float4 ca = *(const float4*)cr;
  float4 cv = *(const float4*)(cr + 4);
  double s = 0.0, d;
  d = (double)xa.x - (double)ca.x; s += d*d;
  d = (double)xa.y - (double)ca.y; s += d*d;
  d = (double)xa.z - (double)ca.z; s += d*d;
  d = (double)xa.w - (double)ca.w; s += d*d;
  d = (double)xb.x - (double)cv.x; s += d*d;
  d = (double)xb.y - (double)cv.y; s += d*d;
  d = (double)xb.z - (double)cv.z; s += d*d;
  d = (double)xb.w - (double)cv.w; s += d*d;
  #pragma unroll
  for (int m = 1; m < 64; m <<= 1) s += shfl_xor_dbl(s, m);
  if (s < best || (s == best && col < bi)) { best = s; bi = col; }
}

__global__ __launch_bounds__(256) void k_refine(
    const float* __restrict__ x, const float* __restrict__ cb,
    const float* __restrict__ cnorm, const uint2* __restrict__ stats,
    unsigned int* __restrict__ bestOut)
{
  int n = blockIdx.x * 4 + (threadIdx.x >> 6);
  int lane = threadIdx.x & 63;
  uint2 st = stats[(size_t)n * NTILES + lane];   // lane t owns stat tile t
  float m1 = __uint_as_float(st.x);
  int   i1 = st.y & 127, i2 = (st.y >> 7) & 127;
  float m2 = m1 + ((st.y >> 14) & 255u) * 0.25f;
  float m3 = m1 + ((st.y >> 22) & 255u) * 0.25f;
  float g = m1;
  #pragma unroll
  for (int m = 1; m < 64; m <<= 1) g = fminf(g, __shfl_xor(g, m, 64));
  float T = g + MARGIN;
  unsigned long long q1 = __ballot(m1 <= T);
  unsigned long long q2 = __ballot(m2 <= T);
  unsigned long long qr = __ballot(m3 <= T);

  const float* xr = x + (size_t)n * DDIM;
  float4 xa = *(const float4*)(xr + lane * 8);
  float4 xb = *(const float4*)(xr + lane * 8 + 4);

  double best = 1e300;
  int bi = 0x7fffffff;

  while (q1) {
    int t = __ffsll(q1) - 1; q1 &= q1 - 1;
    int col = t * 128 + __shfl(i1, t, 64);
    eval64(xa, xb, cb, col, best, bi, lane);
  }
  while (q2) {
    int t = __ffsll(q2) - 1; q2 &= q2 - 1;
    int col = t * 128 + __shfl(i2, t, 64);
    eval64(xa, xb, cb, col, best, bi, lane);
  }
  while (qr) {
    int t = __ffsll(qr) - 1; qr &= qr - 1;
    for (int c2 = 0; c2 < 128; ++c2) {
      int col2 = t * 128 + c2;
      const float* cr = cb + (size_t)col2 * DDIM + lane * 8;
      float4 ca = *(const float4*)cr;
      float4 cv = *(const float4*)(cr + 4);
      float p = xa.x*ca.x + xa.y*ca.y + xa.z*ca.z + xa.w*ca.w
              + xb.x*cv.x + xb.y*cv.y + xb.z*cv.z + xb.w*cv.w;
      #pragma unroll
      for (int m = 1; m < 64; m <<= 1) p += __shfl_xor(p, m, 64);
      float s32 = cnorm[col2] - 2.0f * p;
      if (s32 <= T) {
        double s = 0.0, dd;
        dd = (double)xa.x - (double)ca.x; s += dd*dd;
        dd = (double)xa.y - (double)ca.y; s += dd*dd;
        dd = (double)xa.z - (double)ca.z; s += dd*dd;
        dd = (double)xa.w - (double)ca.w; s += dd*dd;
        dd = (double)xb.x - (double)cv.x; s += dd*dd;
        dd = (double)xb.y - (double)cv.y; s += dd*dd;
        dd = (double)xb.z - (double)cv.z; s += dd*dd;
        dd = (double)xb.w - (double)cv.w; s += dd*dd;
        #pragma unroll
        for (int m = 1; m < 64; m <<= 1) s += shfl_xor_dbl(s, m);
        if (s < best || (s == best && col2 < bi)) { best = s; bi = col2; }
      }
    }
  }
  if (lane == 0) bestOut[n] = (unsigned int)bi;
}

// ---------------- gather ----------------

__global__ __launch_bounds__(256) void k_gather(const float* __restrict__ cb,
                                                const unsigned int* __restrict__ bestIdx,
                                                float* __restrict__ out) {
  int n = blockIdx.x * 4 + (threadIdx.x >> 6);
  int lane = threadIdx.x & 63;
  unsigned int b = bestIdx[n];
  const float4* s = (const float4*)(cb + (size_t)b * DDIM);
  float4* dp = (float4*)(out + (size_t)n * DDIM);
  dp[lane * 2]     = s[lane * 2];
  dp[lane * 2 + 1] = s[lane * 2 + 1];
}

// ---------------- launch ----------------

extern "C" void kernel_launch(void* const* d_in, const int* in_sizes, int n_in,
                              void* d_out, int out_size, void* d_ws, size_t ws_size,
                              hipStream_t stream) {
  const float* x  = (const float*)d_in[0];   // [16384, 512]
  const float* cb = (const float*)d_in[1];   // [8192, 512]
  float* out = (float*)d_out;

  // d_out as scratch until gather: [0,16M) Xbf | [16M,24M) Cbf | [24M,32M) stats
  char* ob = (char*)d_out;
  u16*   Xbf   = (u16*)ob;
  u16*   Cbf   = (u16*)(ob + 16ull * 1024 * 1024);
  uint2* stats = (uint2*)(ob + 24ull * 1024 * 1024);

  char* wsb = (char*)d_ws;
  float* cnorm = (float*)wsb;                            // 32 KB
  unsigned int* bestIdx = (unsigned int*)(wsb + 32 * 1024);

  // allow 128 KB dynamic LDS (best-effort; harmless if already allowed)
  (void)hipFuncSetAttribute((const void*)k_gemm_min,
                            hipFuncAttributeMaxDynamicSharedMemorySize, 131072);

  k_conv_x  <<<4096, 256, 0, stream>>>(x, Xbf);
  k_conv_cb <<<2048, 256, 0, stream>>>(cb, Cbf, cnorm);
  k_gemm_min<<<2048, 512, 131072, stream>>>(Xbf, Cbf, cnorm, stats);
  k_refine  <<<4096, 256, 0, stream>>>(x, cb, cnorm, stats, bestIdx);
  k_gather  <<<4096, 256, 0, stream>>>(cb, bestIdx, out);
}

// Round 6
// 267.592 us; speedup vs baseline: 1.7452x; 1.2803x over previous
//
#include <hip/hip_runtime.h>

// x [16384,512] f32, codebook [8192,512] f32 -> out[n] = codebook[argmin_k ||x_n-c_k||^2]
// 256x256 bf16 MFMA GEMM (swapped operands: A=codebook, B=x so the argmin axis is
// lane-local), 2-deep pipelined, per-lane register top-3 epilogue; guaranteed-inclusive
// fp64 refinement; gather.

#define MROWS 16384
#define KCB   8192
#define DDIM  512
#define BM 256
#define BN 256
#define BK 64
#define NKT (DDIM / BK)      // 8 K-tiles
#define NTILES (KCB / 128)   // 64 stat tiles of 128 cols
#define MARGIN 8.0f

typedef unsigned short u16;
typedef unsigned int uint;
typedef __attribute__((ext_vector_type(8))) short bf16x8;
typedef __attribute__((ext_vector_type(4))) float f32x4;

__device__ inline u16 f2bf(float f) {
  unsigned int u = __float_as_uint(f);
  u += 0x7FFFu + ((u >> 16) & 1u);
  return (u16)(u >> 16);
}

__device__ inline void gload16(const void* g, void* l) {
  __builtin_amdgcn_global_load_lds((const __attribute__((address_space(1))) void*)g,
                                   (__attribute__((address_space(3))) void*)l,
                                   16, 0, 0);
}

__device__ inline double shfl_xor_dbl(double v, int m) {
  long long l = __double_as_longlong(v);
  int lo = (int)(l & 0xffffffffLL), hi = (int)(l >> 32);
  lo = __shfl_xor(lo, m, 64);
  hi = __shfl_xor(hi, m, 64);
  return __longlong_as_double(((long long)hi << 32) | (unsigned long long)(unsigned int)lo);
}

__device__ inline float keyval(uint k) {
  uint u = k & 0xFFFFFF80u;
  uint bits = (u & 0x80000000u) ? (u & 0x7FFFFFFFu) : ~u;
  return __uint_as_float(bits);
}

// ---------------- conversion kernels ----------------

__global__ __launch_bounds__(256) void k_conv_x(const float* __restrict__ x,
                                                u16* __restrict__ xb) {
  size_t i = ((size_t)blockIdx.x * 256 + threadIdx.x) * 8;
  float4 a = *(const float4*)(x + i);
  float4 b = *(const float4*)(x + i + 4);
  union { u16 s[8]; uint4 v; } u;
  u.s[0]=f2bf(a.x); u.s[1]=f2bf(a.y); u.s[2]=f2bf(a.z); u.s[3]=f2bf(a.w);
  u.s[4]=f2bf(b.x); u.s[5]=f2bf(b.y); u.s[6]=f2bf(b.z); u.s[7]=f2bf(b.w);
  *(uint4*)(xb + i) = u.v;
}

__global__ __launch_bounds__(256) void k_conv_cb(const float* __restrict__ cb,
                                                 u16* __restrict__ cbb,
                                                 float* __restrict__ cnorm) {
  int k = blockIdx.x * 4 + (threadIdx.x >> 6);
  int lane = threadIdx.x & 63;
  size_t base = (size_t)k * DDIM + lane * 8;
  float4 a = *(const float4*)(cb + base);
  float4 b = *(const float4*)(cb + base + 4);
  union { u16 s[8]; uint4 v; } u;
  u.s[0]=f2bf(a.x); u.s[1]=f2bf(a.y); u.s[2]=f2bf(a.z); u.s[3]=f2bf(a.w);
  u.s[4]=f2bf(b.x); u.s[5]=f2bf(b.y); u.s[6]=f2bf(b.z); u.s[7]=f2bf(b.w);
  *(uint4*)(cbb + base) = u.v;
  float s = a.x*a.x + a.y*a.y + a.z*a.z + a.w*a.w
          + b.x*b.x + b.y*b.y + b.z*b.z + b.w*b.w;
  #pragma unroll
  for (int m = 1; m < 64; m <<= 1) s += __shfl_xor(s, m, 64);
  if (lane == 0) cnorm[k] = s;
}

// ---------------- 256x256 GEMM + per-lane register top-3 ----------------

__global__ __launch_bounds__(512, 2) void k_gemm_min(
    const u16* __restrict__ Xbf, const u16* __restrict__ Cbf,
    const float* __restrict__ cnorm, uint2* __restrict__ stats)
{
  extern __shared__ u16 lds[];   // [0,32K) X0 | [32K,64K) X1 | [64K,96K) C0 | [96K,128K) C1

  int bid = blockIdx.x;          // 2048 blocks
  int xcd = bid & 7;
  int j   = bid >> 3;
  int mTile = xcd * 8 + (j & 7); // 0..63 (x-row tiles)
  int nTile = j >> 3;            // 0..31 (cb tiles)
  int rowBase = mTile * BM;      // x rows
  int colBase = nTile * BN;      // cb rows

  int tid = threadIdx.x;
  int lane = tid & 63;
  int wv = tid >> 6;     // 0..7
  int wr = wv >> 2;      // 0..1  cb half (MFMA A/M dim)
  int wc = wv & 3;       // 0..3  x quarter (MFMA B/N dim)
  int grp = lane >> 4;
  int l15 = lane & 15;

  // staging: XOR-swizzled global source, linear LDS dest
  const u16 *srcX[4], *srcC[4];
  #pragma unroll
  for (int i = 0; i < 4; ++i) {
    int f = i * 512 + tid;        // chunk 0..2047
    int r = f >> 3;               // tile row 0..255
    int p = f & 7;
    int gc = (p ^ (r & 7)) << 3;
    srcX[i] = Xbf + (size_t)(rowBase + r) * DDIM + gc;
    srcC[i] = Cbf + (size_t)(colBase + r) * DDIM + gc;
  }

  // acc[mi over cb (A/M dim)][ni over x (B/N dim)]
  f32x4 acc[8][4];
  #pragma unroll
  for (int mi = 0; mi < 8; ++mi)
    #pragma unroll
    for (int ni = 0; ni < 4; ++ni)
      acc[mi][ni] = (f32x4){0.f, 0.f, 0.f, 0.f};

#define STAGE(cur_, kt_)                                                     \
  {                                                                          \
    u16* Xd = lds + (cur_) * 16384;                                          \
    u16* Cd = lds + 32768 + (cur_) * 16384;                                  \
    _Pragma("unroll")                                                        \
    for (int i = 0; i < 4; ++i) {                                            \
      gload16(srcX[i] + (kt_) * BK, (void*)(Xd + (i * 512 + wv * 64) * 8));  \
      gload16(srcC[i] + (kt_) * BK, (void*)(Cd + (i * 512 + wv * 64) * 8));  \
    }                                                                        \
  }

  STAGE(0, 0);
  STAGE(1, 1);
  __syncthreads();                 // prologue drain (only exposed latency)

  int cur = 0;
  for (int kt = 0; kt < NKT; ++kt) {
    const u16* Xb = lds + cur * 16384;
    const u16* Cs = lds + 32768 + cur * 16384;
    #pragma unroll
    for (int ks = 0; ks < 2; ++ks) {
      bf16x8 xF[4];
      #pragma unroll
      for (int ni = 0; ni < 4; ++ni) {
        int rX = wc * 64 + ni * 16 + l15;
        xF[ni] = *(const bf16x8*)&Xb[rX * BK + (((ks * 4 + grp) ^ (rX & 7)) << 3)];
      }
      #pragma unroll
      for (int mi = 0; mi < 8; ++mi) {
        int rC = wr * 128 + mi * 16 + l15;
        bf16x8 cF = *(const bf16x8*)&Cs[rC * BK + (((ks * 4 + grp) ^ (rC & 7)) << 3)];
        #pragma unroll
        for (int ni = 0; ni < 4; ++ni)
          acc[mi][ni] = __builtin_amdgcn_mfma_f32_16x16x32_bf16(cF, xF[ni], acc[mi][ni], 0, 0, 0);
      }
    }
    __syncthreads();               // frees buf[cur]; drains loads issued LAST iter
    if (kt + 2 < NKT) STAGE(cur, kt + 2);
    cur ^= 1;
  }
#undef STAGE

  // ---- epilogue: per-lane register top-3 ----
  // D[m=cb][n=x]: x-row = lane&15 (col), cb = (lane>>4)*4 + reg (row) per m89.
  // Lane holds, for x-row (wc*64+ni*16+l15), cb_local = mi*16+grp*4+reg over mi,reg:
  // 32 scores in registers -> register top-3, then merge the 4 lane-groups (xor 16,32).
#define INS(st1, st2, st3, kx)                                     \
  { uint kk_ = (kx);                                               \
    bool lt1 = kk_ < st1, lt2 = kk_ < st2, lt3 = kk_ < st3;        \
    st3 = lt3 ? (lt2 ? st2 : kk_) : st3;                           \
    st2 = lt2 ? (lt1 ? st1 : kk_) : st2;                           \
    st1 = lt1 ? kk_ : st1; }

  uint t1[4], t2[4], t3[4];
  #pragma unroll
  for (int ni = 0; ni < 4; ++ni) { t1[ni] = 0xFFFFFFFFu; t2[ni] = 0xFFFFFFFFu; t3[ni] = 0xFFFFFFFFu; }

  #pragma unroll
  for (int mi = 0; mi < 8; ++mi) {
    float cnv[4];
    *(float4*)cnv = *(const float4*)&cnorm[colBase + wr * 128 + mi * 16 + grp * 4];
    #pragma unroll
    for (int ni = 0; ni < 4; ++ni) {
      #pragma unroll
      for (int rg = 0; rg < 4; ++rg) {
        float v = cnv[rg] - 2.0f * acc[mi][ni][rg];
        uint u = __float_as_uint(v);
        u = ((int)u < 0) ? ~u : (u | 0x80000000u);
        uint key = (u & 0xFFFFFF80u) | (uint)(mi * 16 + grp * 4 + rg);
        INS(t1[ni], t2[ni], t3[ni], key);
      }
    }
  }
  #pragma unroll
  for (int ni = 0; ni < 4; ++ni) {
    #pragma unroll
    for (int mk = 16; mk <= 32; mk <<= 1) {
      uint o1 = (uint)__shfl_xor((int)t1[ni], mk, 64);
      uint o2 = (uint)__shfl_xor((int)t2[ni], mk, 64);
      uint o3 = (uint)__shfl_xor((int)t3[ni], mk, 64);
      INS(t1[ni], t2[ni], t3[ni], o1);
      INS(t1[ni], t2[ni], t3[ni], o2);
      INS(t1[ni], t2[ni], t3[ni], o3);
    }
  }
#undef INS
  if (grp == 0) {    // lanes 0..15 hold final result for their x-row
    #pragma unroll
    for (int ni = 0; ni < 4; ++ni) {
      float v1 = keyval(t1[ni]), v2 = keyval(t2[ni]), v3 = keyval(t3[ni]);
      uint i1 = t1[ni] & 127u, i2 = t2[ni] & 127u;
      uint d2 = min(255u, (uint)((v2 - v1) * 4.0f));   // floor -> conservative-low
      uint d3 = min(255u, (uint)((v3 - v1) * 4.0f));
      uint2 st;
      st.x = __float_as_uint(v1);
      st.y = i1 | (i2 << 7) | (d2 << 14) | (d3 << 22);
      int xrow = rowBase + wc * 64 + ni * 16 + l15;
      stats[(size_t)xrow * NTILES + nTile * 2 + wr] = st;
    }
  }
}

// ---------------- fp64 refinement (one wave per row) ----------------

__device__ inline void eval64(const float4& xa, const float4& xb,
                              const float* __restrict__ cb, int col,
                              double& best, int& bi, int lane) {
  const float* cr = cb + (size_t)col * DDIM + lane * 8;
  float4 ca = *(const float4*)cr;
  float4 cv = *(const float4*)(cr + 4);
  double s = 0.0, d;
  d = (double)xa.x - (double)ca.x; s += d*d;
  d = (double)xa.y - (double)ca.y; s += d*d;
  d = (double)xa.z - (double)ca.z; s += d*d;
  d = (double)xa.w - (double)ca.w; s += d*d;
  d = (double)xb.x - (double)cv.x; s += d*d;
  d = (double)xb.y - (double)cv.y; s += d*d;
  d = (double)xb.z - (double)cv.z; s += d*d;
  d = (double)xb.w - (double)cv.w; s += d*d;
  #pragma unroll
  for (int m = 1; m < 64; m <<= 1) s += shfl_xor_dbl(s, m);
  if (s < best || (s == best && col < bi)) { best = s; bi = col; }
}

__global__ __launch_bounds__(256) void k_refine(
    const float* __restrict__ x, const float* __restrict__ cb,
    const float* __restrict__ cnorm, const uint2* __restrict__ stats,
    unsigned int* __restrict__ bestOut)
{
  int n = blockIdx.x * 4 + (threadIdx.x >> 6);
  int lane = threadIdx.x & 63;
  uint2 st = stats[(size_t)n * NTILES + lane];   // lane t owns stat tile t
  float m1 = __uint_as_float(st.x);
  int   i1 = st.y & 127, i2 = (st.y >> 7) & 127;
  float m2 = m1 + ((st.y >> 14) & 255u) * 0.25f;
  float m3 = m1 + ((st.y >> 22) & 255u) * 0.25f;
  float g = m1;
  #pragma unroll
  for (int m = 1; m < 64; m <<= 1) g = fminf(g, __shfl_xor(g, m, 64));
  float T = g + MARGIN;
  unsigned long long q1 = __ballot(m1 <= T);
  unsigned long long q2 = __ballot(m2 <= T);
  unsigned long long qr = __ballot(m3 <= T);

  const float* xr = x + (size_t)n * DDIM;
  float4 xa = *(const float4*)(xr + lane * 8);
  float4 xb = *(const float4*)(xr + lane * 8 + 4);

  double best = 1e300;
  int bi = 0x7fffffff;

  while (q1) {
    int t = __ffsll(q1) - 1; q1 &= q1 - 1;
    int col = t * 128 + __shfl(i1, t, 64);
    eval64(xa, xb, cb, col, best, bi, lane);
  }
  while (q2) {
    int t = __ffsll(q2) - 1; q2 &= q2 - 1;
    int col = t * 128 + __shfl(i2, t, 64);
    eval64(xa, xb, cb, col, best, bi, lane);
  }
  while (qr) {
    int t = __ffsll(qr) - 1; qr &= qr - 1;
    for (int c2 = 0; c2 < 128; ++c2) {
      int col2 = t * 128 + c2;
      const float* cr = cb + (size_t)col2 * DDIM + lane * 8;
      float4 ca = *(const float4*)cr;
      float4 cv = *(const float4*)(cr + 4);
      float p = xa.x*ca.x + xa.y*ca.y + xa.z*ca.z + xa.w*ca.w
              + xb.x*cv.x + xb.y*cv.y + xb.z*cv.z + xb.w*cv.w;
      #pragma unroll
      for (int m = 1; m < 64; m <<= 1) p += __shfl_xor(p, m, 64);
      float s32 = cnorm[col2] - 2.0f * p;
      if (s32 <= T) {
        double s = 0.0, dd;
        dd = (double)xa.x - (double)ca.x; s += dd*dd;
        dd = (double)xa.y - (double)ca.y; s += dd*dd;
        dd = (double)xa.z - (double)ca.z; s += dd*dd;
        dd = (double)xa.w - (double)ca.w; s += dd*dd;
        dd = (double)xb.x - (double)cv.x; s += dd*dd;
        dd = (double)xb.y - (double)cv.y; s += dd*dd;
        dd = (double)xb.z - (double)cv.z; s += dd*dd;
        dd = (double)xb.w - (double)cv.w; s += dd*dd;
        #pragma unroll
        for (int m = 1; m < 64; m <<= 1) s += shfl_xor_dbl(s, m);
        if (s < best || (s == best && col2 < bi)) { best = s; bi = col2; }
      }
    }
  }
  if (lane == 0) bestOut[n] = (unsigned int)bi;
}

// ---------------- gather ----------------

__global__ __launch_bounds__(256) void k_gather(const float* __restrict__ cb,
                                                const unsigned int* __restrict__ bestIdx,
                                                float* __restrict__ out) {
  int n = blockIdx.x * 4 + (threadIdx.x >> 6);
  int lane = threadIdx.x & 63;
  unsigned int b = bestIdx[n];
  const float4* s = (const float4*)(cb + (size_t)b * DDIM);
  float4* dp = (float4*)(out + (size_t)n * DDIM);
  dp[lane * 2]     = s[lane * 2];
  dp[lane * 2 + 1] = s[lane * 2 + 1];
}

// ---------------- launch ----------------

extern "C" void kernel_launch(void* const* d_in, const int* in_sizes, int n_in,
                              void* d_out, int out_size, void* d_ws, size_t ws_size,
                              hipStream_t stream) {
  const float* x  = (const float*)d_in[0];   // [16384, 512]
  const float* cb = (const float*)d_in[1];   // [8192, 512]
  float* out = (float*)d_out;

  // d_out as scratch until gather: [0,16M) Xbf | [16M,24M) Cbf | [24M,32M) stats
  char* ob = (char*)d_out;
  u16*   Xbf   = (u16*)ob;
  u16*   Cbf   = (u16*)(ob + 16ull * 1024 * 1024);
  uint2* stats = (uint2*)(ob + 24ull * 1024 * 1024);

  char* wsb = (char*)d_ws;
  float* cnorm = (float*)wsb;                            // 32 KB
  unsigned int* bestIdx = (unsigned int*)(wsb + 32 * 1024);

  (void)hipFuncSetAttribute((const void*)k_gemm_min,
                            hipFuncAttributeMaxDynamicSharedMemorySize, 131072);

  k_conv_x  <<<4096, 256, 0, stream>>>(x, Xbf);
  k_conv_cb <<<2048, 256, 0, stream>>>(cb, Cbf, cnorm);
  k_gemm_min<<<2048, 512, 131072, stream>>>(Xbf, Cbf, cnorm, stats);
  k_refine  <<<4096, 256, 0, stream>>>(x, cb, cnorm, stats, bestIdx);
  k_gather  <<<4096, 256, 0, stream>>>(cb, bestIdx, out);
}

// Round 7
// 257.372 us; speedup vs baseline: 1.8145x; 1.0397x over previous
//
#include <hip/hip_runtime.h>

// x [16384,512] f32, codebook [8192,512] f32 -> out[n] = codebook[argmin_k ||x_n-c_k||^2]
// 256x256 bf16 MFMA GEMM with m201-style 8-phase counted-vmcnt schedule (T3+T4+T5),
// operand-swapped (A=codebook, B=x) so argmin axis is lane-local; per-lane register
// top-3 epilogue; guaranteed-inclusive fp64 refinement; gather.

#define MROWS 16384
#define KCB   8192
#define DDIM  512
#define NKT   8              // K-tiles of BK=64
#define NTILES (KCB / 128)   // 64 stat tiles of 128 cols
#define MARGIN 8.0f

typedef unsigned short u16;
typedef unsigned int uint;
typedef __attribute__((ext_vector_type(8))) short bf16x8;
typedef __attribute__((ext_vector_type(4))) float f32x4;

__device__ inline u16 f2bf(float f) {
  unsigned int u = __float_as_uint(f);
  u += 0x7FFFu + ((u >> 16) & 1u);
  return (u16)(u >> 16);
}

__device__ inline void gload16(const void* g, void* l) {
  __builtin_amdgcn_global_load_lds((const __attribute__((address_space(1))) void*)g,
                                   (__attribute__((address_space(3))) void*)l,
                                   16, 0, 0);
}

__device__ inline double shfl_xor_dbl(double v, int m) {
  long long l = __double_as_longlong(v);
  int lo = (int)(l & 0xffffffffLL), hi = (int)(l >> 32);
  lo = __shfl_xor(lo, m, 64);
  hi = __shfl_xor(hi, m, 64);
  return __longlong_as_double(((long long)hi << 32) | (unsigned long long)(unsigned int)lo);
}

__device__ inline float keyval(uint k) {
  uint u = k & 0xFFFFFF80u;
  uint bits = (u & 0x80000000u) ? (u & 0x7FFFFFFFu) : ~u;
  return __uint_as_float(bits);
}

// ---------------- conversion kernels ----------------

__global__ __launch_bounds__(256) void k_conv_x(const float* __restrict__ x,
                                                u16* __restrict__ xb) {
  size_t i = ((size_t)blockIdx.x * 256 + threadIdx.x) * 8;
  float4 a = *(const float4*)(x + i);
  float4 b = *(const float4*)(x + i + 4);
  union { u16 s[8]; uint4 v; } u;
  u.s[0]=f2bf(a.x); u.s[1]=f2bf(a.y); u.s[2]=f2bf(a.z); u.s[3]=f2bf(a.w);
  u.s[4]=f2bf(b.x); u.s[5]=f2bf(b.y); u.s[6]=f2bf(b.z); u.s[7]=f2bf(b.w);
  *(uint4*)(xb + i) = u.v;
}

__global__ __launch_bounds__(256) void k_conv_cb(const float* __restrict__ cb,
                                                 u16* __restrict__ cbb,
                                                 float* __restrict__ cnorm) {
  int k = blockIdx.x * 4 + (threadIdx.x >> 6);
  int lane = threadIdx.x & 63;
  size_t base = (size_t)k * DDIM + lane * 8;
  float4 a = *(const float4*)(cb + base);
  float4 b = *(const float4*)(cb + base + 4);
  union { u16 s[8]; uint4 v; } u;
  u.s[0]=f2bf(a.x); u.s[1]=f2bf(a.y); u.s[2]=f2bf(a.z); u.s[3]=f2bf(a.w);
  u.s[4]=f2bf(b.x); u.s[5]=f2bf(b.y); u.s[6]=f2bf(b.z); u.s[7]=f2bf(b.w);
  *(uint4*)(cbb + base) = u.v;
  float s = a.x*a.x + a.y*a.y + a.z*a.z + a.w*a.w
          + b.x*b.x + b.y*b.y + b.z*b.z + b.w*b.w;
  #pragma unroll
  for (int m = 1; m < 64; m <<= 1) s += __shfl_xor(s, m, 64);
  if (lane == 0) cnorm[k] = s;
}

// ---------------- 256x256 GEMM, 8-phase schedule ----------------
// LDS map (u16 elems): A: buf b at [b*16384, +16384): region h at +h*8192,
//   band w(=wr) at +w*4096, row rr (=q*16+l15) at +rr*64, swizzled 16B chunks.
// B: at [32768 + b*16384): row-major [256][64], XOR-8 chunk swizzle.

__global__ __launch_bounds__(512, 2) void k_gemm_min(
    const u16* __restrict__ Xbf, const u16* __restrict__ Cbf,
    const float* __restrict__ cnorm, uint2* __restrict__ stats)
{
  extern __shared__ __align__(16) u16 lds[];

  int bid = blockIdx.x;          // 2048 blocks
  int xcd = bid & 7;
  int j   = bid >> 3;
  int mTile = xcd * 8 + (j & 7); // x-row tiles 0..63
  int nTile = j >> 3;            // cb tiles 0..31
  int rowBase = mTile * 256;     // x rows
  int colBase = nTile * 256;     // cb rows

  int tid = threadIdx.x;
  int lane = tid & 63;
  int wv = tid >> 6;     // 0..7
  int wr = wv >> 2;      // 0..1  cb half (MFMA A/M dim)
  int wc = wv & 3;       // 0..3  x quarter (MFMA B/N dim)
  int grp = lane >> 4;
  int l15 = lane & 15;

  // stage source base pointers (inverse-swizzled global chunk)
  const int rr = tid >> 3;             // 0..63
  const int pc = (tid & 7) ^ (rr & 7); // swizzled source chunk
  const u16* pA = Cbf + (size_t)(colBase + rr) * DDIM + pc * 8;
  const u16* pB = Xbf + (size_t)(rowBase + rr) * DDIM + pc * 8;

  // reader LDS offsets (u16 elems), per k-slot
  const int m7 = l15 & 7;
  const int ch0 = (grp ^ m7);          // ks=0 chunk
  const int ch1 = ch0 ^ 4;             // ks=1 chunk
  const int cOff0 = wr * 4096 + l15 * 64 + ch0 * 8;
  const int cOff1 = wr * 4096 + l15 * 64 + ch1 * 8;
  const int xOff0 = wc * 4096 + l15 * 64 + ch0 * 8;
  const int xOff1 = wc * 4096 + l15 * 64 + ch1 * 8;

  f32x4 acc[8][4];
  #pragma unroll
  for (int mi = 0; mi < 8; ++mi)
    #pragma unroll
    for (int ni = 0; ni < 4; ++ni)
      acc[mi][ni] = (f32x4){0.f, 0.f, 0.f, 0.f};

  // ---- prologue: stage tile 0 into buf0: B-h0, B-h1, A-h0, A-h1 (order matters) ----
  gload16(pB,           (void*)&lds[32768 + tid * 8]);
  gload16(pB + 32768,   (void*)&lds[32768 + 4096 + tid * 8]);          // band1 (+64 rows)
  gload16(pB + 65536,   (void*)&lds[32768 + 8192 + tid * 8]);          // hb1 band0 (+128 rows)
  gload16(pB + 98304,   (void*)&lds[32768 + 12288 + tid * 8]);         // hb1 band1
  gload16(pA,           (void*)&lds[tid * 8]);                          // A h0 w0
  gload16(pA + 65536,   (void*)&lds[4096 + tid * 8]);                   // A h0 w1 (+128 rows)
  gload16(pA + 32768,   (void*)&lds[8192 + tid * 8]);                   // A h1 w0 (+64 rows)
  gload16(pA + 98304,   (void*)&lds[8192 + 4096 + tid * 8]);            // A h1 w1

  bf16x8 xF[4];

  #pragma unroll
  for (int it = 0; it < 4; ++it) {
    #pragma unroll
    for (int ph = 0; ph < 8; ++ph) {
      const int b  = ph >> 2;          // read buf / tile parity
      const int s  = ph & 3;
      const int h  = s & 1;
      const int ks = s >> 1;
      const int tauS = 2 * it + 1 + (ph >> 2);   // tile being staged
      const int bS = (ph < 4) ? 1 : 0;           // stage buf

      // certify prior stages (counted vmcnt, never a drain except the one edge case)
      if ((ph & 2) == 0) {
        if (it == 3 && ph == 5) { asm volatile("s_waitcnt vmcnt(0)" ::: "memory"); }
        else                    { asm volatile("s_waitcnt vmcnt(2)" ::: "memory"); }
      }
      __builtin_amdgcn_s_barrier();
      __builtin_amdgcn_sched_barrier(0);

      // ds-loads for this phase
      bf16x8 cF[4];
      #pragma unroll
      for (int q = 0; q < 4; ++q)
        cF[q] = *(const bf16x8*)&lds[b * 16384 + h * 8192 + q * 1024 + (ks ? cOff1 : cOff0)];
      if (h == 0) {
        #pragma unroll
        for (int ni = 0; ni < 4; ++ni)
          xF[ni] = *(const bf16x8*)&lds[32768 + b * 16384 + ni * 1024 + (ks ? xOff1 : xOff0)];
      }

      // stage one half-tile (skipped for nonexistent tile 8)
      if (!(it == 3 && ph >= 4)) {
        if (s < 2) {       // B half s: rows s*128..+128 (two 64-row bands)
          gload16(pB + s * 65536 + tauS * 64,
                  (void*)&lds[32768 + bS * 16384 + s * 8192 + tid * 8]);
          gload16(pB + s * 65536 + 32768 + tauS * 64,
                  (void*)&lds[32768 + bS * 16384 + s * 8192 + 4096 + tid * 8]);
        } else {           // A region h=s-2: bands w=0,1
          const int ha = s - 2;
          gload16(pA + ha * 32768 + tauS * 64,
                  (void*)&lds[bS * 16384 + ha * 8192 + tid * 8]);
          gload16(pA + ha * 32768 + 65536 + tauS * 64,
                  (void*)&lds[bS * 16384 + ha * 8192 + 4096 + tid * 8]);
        }
      }

      asm volatile("s_waitcnt lgkmcnt(0)" ::: "memory");
      __builtin_amdgcn_sched_barrier(0);
      __builtin_amdgcn_s_setprio(1);
      #pragma unroll
      for (int q = 0; q < 4; ++q)
        #pragma unroll
        for (int ni = 0; ni < 4; ++ni)
          acc[h * 4 + q][ni] =
            __builtin_amdgcn_mfma_f32_16x16x32_bf16(cF[q], xF[ni], acc[h * 4 + q][ni], 0, 0, 0);
      __builtin_amdgcn_s_setprio(0);
    }
  }

  // ---- epilogue: per-lane register top-3 (round-6 verified) ----
  // D[m=cb][n=x]: x-row = lane&15, cb = (lane>>4)*4 + reg
#define INS(st1, st2, st3, kx)                                     \
  { uint kk_ = (kx);                                               \
    bool lt1 = kk_ < st1, lt2 = kk_ < st2, lt3 = kk_ < st3;        \
    st3 = lt3 ? (lt2 ? st2 : kk_) : st3;                           \
    st2 = lt2 ? (lt1 ? st1 : kk_) : st2;                           \
    st1 = lt1 ? kk_ : st1; }

  uint t1[4], t2[4], t3[4];
  #pragma unroll
  for (int ni = 0; ni < 4; ++ni) { t1[ni] = 0xFFFFFFFFu; t2[ni] = 0xFFFFFFFFu; t3[ni] = 0xFFFFFFFFu; }

  #pragma unroll
  for (int mi = 0; mi < 8; ++mi) {
    float cnv[4];
    *(float4*)cnv = *(const float4*)&cnorm[colBase + wr * 128 + mi * 16 + grp * 4];
    #pragma unroll
    for (int ni = 0; ni < 4; ++ni) {
      #pragma unroll
      for (int rg = 0; rg < 4; ++rg) {
        float v = cnv[rg] - 2.0f * acc[mi][ni][rg];
        uint u = __float_as_uint(v);
        u = ((int)u < 0) ? ~u : (u | 0x80000000u);
        uint key = (u & 0xFFFFFF80u) | (uint)(mi * 16 + grp * 4 + rg);
        INS(t1[ni], t2[ni], t3[ni], key);
      }
    }
  }
  #pragma unroll
  for (int ni = 0; ni < 4; ++ni) {
    #pragma unroll
    for (int mk = 16; mk <= 32; mk <<= 1) {
      uint o1 = (uint)__shfl_xor((int)t1[ni], mk, 64);
      uint o2 = (uint)__shfl_xor((int)t2[ni], mk, 64);
      uint o3 = (uint)__shfl_xor((int)t3[ni], mk, 64);
      INS(t1[ni], t2[ni], t3[ni], o1);
      INS(t1[ni], t2[ni], t3[ni], o2);
      INS(t1[ni], t2[ni], t3[ni], o3);
    }
  }
#undef INS
  if (grp == 0) {    // lanes 0..15 hold final result for their x-row
    #pragma unroll
    for (int ni = 0; ni < 4; ++ni) {
      float v1 = keyval(t1[ni]), v2 = keyval(t2[ni]), v3 = keyval(t3[ni]);
      uint i1 = t1[ni] & 127u, i2 = t2[ni] & 127u;
      uint d2 = min(255u, (uint)((v2 - v1) * 4.0f));   // floor -> conservative-low
      uint d3 = min(255u, (uint)((v3 - v1) * 4.0f));
      uint2 st;
      st.x = __float_as_uint(v1);
      st.y = i1 | (i2 << 7) | (d2 << 14) | (d3 << 22);
      int xrow = rowBase + wc * 64 + ni * 16 + l15;
      stats[(size_t)xrow * NTILES + nTile * 2 + wr] = st;
    }
  }
}

// ---------------- fp64 refinement (one wave per row) ----------------

__device__ inline void eval64(const float4& xa, const float4& xb,
                              const float* __restrict__ cb, int col,
                              double& best, int& bi, int lane) {
  const float* cr = cb + (size_t)col * DDIM + lane * 8;
  float4 ca = *(const float4*)cr;
  float4 cv = *(const float4*)(cr + 4);
  double s = 0.0, d;
  d = (double)xa.x - (double)ca.x; s += d*d;
  d = (double)xa.y - (double)ca.y; s += d*d;
  d = (double)xa.z - (double)ca.z; s += d*d;
  d = (double)xa.w - (double)ca.w; s += d*d;
  d = (double)xb.x - (double)cv.x; s += d*d;
  d = (double)xb.y - (double)cv.y; s += d*d;
  d = (double)xb.z - (double)cv.z; s += d*d;
  d = (double)xb.w - (double)cv.w; s += d*d;
  #pragma unroll
  for (int m = 1; m < 64; m <<= 1) s += shfl_xor_dbl(s, m);
  if (s < best || (s == best && col < bi)) { best = s; bi = col; }
}

__global__ __launch_bounds__(256) void k_refine(
    const float* __restrict__ x, const float* __restrict__ cb,
    const float* __restrict__ cnorm, const uint2* __restrict__ stats,
    unsigned int* __restrict__ bestOut)
{
  int n = blockIdx.x * 4 + (threadIdx.x >> 6);
  int lane = threadIdx.x & 63;
  uint2 st = stats[(size_t)n * NTILES + lane];   // lane t owns stat tile t
  float m1 = __uint_as_float(st.x);
  int   i1 = st.y & 127, i2 = (st.y >> 7) & 127;
  float m2 = m1 + ((st.y >> 14) & 255u) * 0.25f;
  float m3 = m1 + ((st.y >> 22) & 255u) * 0.25f;
  float g = m1;
  #pragma unroll
  for (int m = 1; m < 64; m <<= 1) g = fminf(g, __shfl_xor(g, m, 64));
  float T = g + MARGIN;
  unsigned long long q1 = __ballot(m1 <= T);
  unsigned long long q2 = __ballot(m2 <= T);
  unsigned long long qr = __ballot(m3 <= T);

  const float* xr = x + (size_t)n * DDIM;
  float4 xa = *(const float4*)(xr + lane * 8);
  float4 xb = *(const float4*)(xr + lane * 8 + 4);

  double best = 1e300;
  int bi = 0x7fffffff;

  while (q1) {
    int t = __ffsll(q1) - 1; q1 &= q1 - 1;
    int col = t * 128 + __shfl(i1, t, 64);
    eval64(xa, xb, cb, col, best, bi, lane);
  }
  while (q2) {
    int t = __ffsll(q2) - 1; q2 &= q2 - 1;
    int col = t * 128 + __shfl(i2, t, 64);
    eval64(xa, xb, cb, col, best, bi, lane);
  }
  while (qr) {
    int t = __ffsll(qr) - 1; qr &= qr - 1;
    for (int c2 = 0; c2 < 128; ++c2) {
      int col2 = t * 128 + c2;
      const float* cr = cb + (size_t)col2 * DDIM + lane * 8;
      float4 ca = *(const float4*)cr;
      float4 cv = *(const float4*)(cr + 4);
      float p = xa.x*ca.x + xa.y*ca.y + xa.z*ca.z + xa.w*ca.w
              + xb.x*cv.x + xb.y*cv.y + xb.z*cv.z + xb.w*cv.w;
      #pragma unroll
      for (int m = 1; m < 64; m <<= 1) p += __shfl_xor(p, m, 64);
      float s32 = cnorm[col2] - 2.0f * p;
      if (s32 <= T) {
        double s = 0.0, dd;
        dd = (double)xa.x - (double)ca.x; s += dd*dd;
        dd = (double)xa.y - (double)ca.y; s += dd*dd;
        dd = (double)xa.z - (double)ca.z; s += dd*dd;
        dd = (double)xa.w - (double)ca.w; s += dd*dd;
        dd = (double)xb.x - (double)cv.x; s += dd*dd;
        dd = (double)xb.y - (double)cv.y; s += dd*dd;
        dd = (double)xb.z - (double)cv.z; s += dd*dd;
        dd = (double)xb.w - (double)cv.w; s += dd*dd;
        #pragma unroll
        for (int m = 1; m < 64; m <<= 1) s += shfl_xor_dbl(s, m);
        if (s < best || (s == best && col2 < bi)) { best = s; bi = col2; }
      }
    }
  }
  if (lane == 0) bestOut[n] = (unsigned int)bi;
}

// ---------------- gather ----------------

__global__ __launch_bounds__(256) void k_gather(const float* __restrict__ cb,
                                                const unsigned int* __restrict__ bestIdx,
                                                float* __restrict__ out) {
  int n = blockIdx.x * 4 + (threadIdx.x >> 6);
  int lane = threadIdx.x & 63;
  unsigned int b = bestIdx[n];
  const float4* s = (const float4*)(cb + (size_t)b * DDIM);
  float4* dp = (float4*)(out + (size_t)n * DDIM);
  dp[lane * 2]     = s[lane * 2];
  dp[lane * 2 + 1] = s[lane * 2 + 1];
}

// ---------------- launch ----------------

extern "C" void kernel_launch(void* const* d_in, const int* in_sizes, int n_in,
                              void* d_out, int out_size, void* d_ws, size_t ws_size,
                              hipStream_t stream) {
  const float* x  = (const float*)d_in[0];   // [16384, 512]
  const float* cb = (const float*)d_in[1];   // [8192, 512]
  float* out = (float*)d_out;

  // d_out as scratch until gather: [0,16M) Xbf | [16M,24M) Cbf | [24M,32M) stats
  char* ob = (char*)d_out;
  u16*   Xbf   = (u16*)ob;
  u16*   Cbf   = (u16*)(ob + 16ull * 1024 * 1024);
  uint2* stats = (uint2*)(ob + 24ull * 1024 * 1024);

  char* wsb = (char*)d_ws;
  float* cnorm = (float*)wsb;                            // 32 KB
  unsigned int* bestIdx = (unsigned int*)(wsb + 32 * 1024);

  (void)hipFuncSetAttribute((const void*)k_gemm_min,
                            hipFuncAttributeMaxDynamicSharedMemorySize, 131072);

  k_conv_x  <<<4096, 256, 0, stream>>>(x, Xbf);
  k_conv_cb <<<2048, 256, 0, stream>>>(cb, Cbf, cnorm);
  k_gemm_min<<<2048, 512, 131072, stream>>>(Xbf, Cbf, cnorm, stats);
  k_refine  <<<4096, 256, 0, stream>>>(x, cb, cnorm, stats, bestIdx);
  k_gather  <<<4096, 256, 0, stream>>>(cb, bestIdx, out);
}

// Round 8
// 256.026 us; speedup vs baseline: 1.8241x; 1.0053x over previous
//
#include <hip/hip_runtime.h>

// x [16384,512] f32, codebook [8192,512] f32 -> out[n] = codebook[argmin_k ||x_n-c_k||^2]
// 256x256 bf16 MFMA GEMM with read-ahead register pipeline: phase p issues ds_reads for
// p+1 (reg double-buffer), counted lgkmcnt before MFMA, counted vmcnt(2) once per K-tile.
// Operand-swapped (A=codebook, B=x) so argmin axis is lane-local; per-lane register
// top-3 epilogue; guaranteed-inclusive fp64 refinement; gather.

#define MROWS 16384
#define KCB   8192
#define DDIM  512
#define NTILES (KCB / 128)   // 64 stat tiles of 128 cols
#define MARGIN 8.0f

typedef unsigned short u16;
typedef unsigned int uint;
typedef __attribute__((ext_vector_type(8))) short bf16x8;
typedef __attribute__((ext_vector_type(4))) float f32x4;

__device__ inline u16 f2bf(float f) {
  unsigned int u = __float_as_uint(f);
  u += 0x7FFFu + ((u >> 16) & 1u);
  return (u16)(u >> 16);
}

__device__ inline void gload16(const void* g, void* l) {
  __builtin_amdgcn_global_load_lds((const __attribute__((address_space(1))) void*)g,
                                   (__attribute__((address_space(3))) void*)l,
                                   16, 0, 0);
}

__device__ inline double shfl_xor_dbl(double v, int m) {
  long long l = __double_as_longlong(v);
  int lo = (int)(l & 0xffffffffLL), hi = (int)(l >> 32);
  lo = __shfl_xor(lo, m, 64);
  hi = __shfl_xor(hi, m, 64);
  return __longlong_as_double(((long long)hi << 32) | (unsigned long long)(unsigned int)lo);
}

__device__ inline float keyval(uint k) {
  uint u = k & 0xFFFFFF80u;
  uint bits = (u & 0x80000000u) ? (u & 0x7FFFFFFFu) : ~u;
  return __uint_as_float(bits);
}

// ---------------- conversion kernels ----------------

__global__ __launch_bounds__(256) void k_conv_x(const float* __restrict__ x,
                                                u16* __restrict__ xb) {
  size_t i = ((size_t)blockIdx.x * 256 + threadIdx.x) * 8;
  float4 a = *(const float4*)(x + i);
  float4 b = *(const float4*)(x + i + 4);
  union { u16 s[8]; uint4 v; } u;
  u.s[0]=f2bf(a.x); u.s[1]=f2bf(a.y); u.s[2]=f2bf(a.z); u.s[3]=f2bf(a.w);
  u.s[4]=f2bf(b.x); u.s[5]=f2bf(b.y); u.s[6]=f2bf(b.z); u.s[7]=f2bf(b.w);
  *(uint4*)(xb + i) = u.v;
}

__global__ __launch_bounds__(256) void k_conv_cb(const float* __restrict__ cb,
                                                 u16* __restrict__ cbb,
                                                 float* __restrict__ cnorm) {
  int k = blockIdx.x * 4 + (threadIdx.x >> 6);
  int lane = threadIdx.x & 63;
  size_t base = (size_t)k * DDIM + lane * 8;
  float4 a = *(const float4*)(cb + base);
  float4 b = *(const float4*)(cb + base + 4);
  union { u16 s[8]; uint4 v; } u;
  u.s[0]=f2bf(a.x); u.s[1]=f2bf(a.y); u.s[2]=f2bf(a.z); u.s[3]=f2bf(a.w);
  u.s[4]=f2bf(b.x); u.s[5]=f2bf(b.y); u.s[6]=f2bf(b.z); u.s[7]=f2bf(b.w);
  *(uint4*)(cbb + base) = u.v;
  float s = a.x*a.x + a.y*a.y + a.z*a.z + a.w*a.w
          + b.x*b.x + b.y*b.y + b.z*b.z + b.w*b.w;
  #pragma unroll
  for (int m = 1; m < 64; m <<= 1) s += __shfl_xor(s, m, 64);
  if (lane == 0) cnorm[k] = s;
}

// ---------------- 256x256 GEMM, read-ahead pipelined ----------------
// LDS map (u16): A buf b: [b*16384,+16384): region h at +h*8192, band w at +w*4096,
//   row rr at +rr*64 (XOR-8 chunk swizzle). B buf b: [32768+b*16384): [256][64] rows.

__global__ __launch_bounds__(512, 2) void k_gemm_min(
    const u16* __restrict__ Xbf, const u16* __restrict__ Cbf,
    const float* __restrict__ cnorm, uint2* __restrict__ stats)
{
  extern __shared__ __align__(16) u16 lds[];

  int bid = blockIdx.x;          // 2048 blocks
  int xcd = bid & 7;
  int j   = bid >> 3;
  int mTile = xcd * 8 + (j & 7); // x-row tiles 0..63
  int nTile = j >> 3;            // cb tiles 0..31
  int rowBase = mTile * 256;     // x rows
  int colBase = nTile * 256;     // cb rows

  int tid = threadIdx.x;
  int lane = tid & 63;
  int wv = tid >> 6;     // 0..7
  int wr = wv >> 2;      // 0..1  cb half (MFMA A/M dim)
  int wc = wv & 3;       // 0..3  x quarter (MFMA B/N dim)
  int grp = lane >> 4;
  int l15 = lane & 15;

  // stage source base (inverse-swizzled global chunk)
  const int rr = tid >> 3;             // 0..63
  const int pc = (tid & 7) ^ (rr & 7);
  const u16* pA = Cbf + (size_t)(colBase + rr) * DDIM + pc * 8;
  const u16* pB = Xbf + (size_t)(rowBase + rr) * DDIM + pc * 8;

  // reader LDS offsets, per k-slot ks
  const int m7 = l15 & 7;
  const int ch0 = (grp ^ m7);
  const int ch1 = ch0 ^ 4;
  const int cOff0 = wr * 4096 + l15 * 64 + ch0 * 8;
  const int cOff1 = wr * 4096 + l15 * 64 + ch1 * 8;
  const int xOff0 = wc * 4096 + l15 * 64 + ch0 * 8;
  const int xOff1 = wc * 4096 + l15 * 64 + ch1 * 8;

  f32x4 acc[8][4];
  #pragma unroll
  for (int mi = 0; mi < 8; ++mi)
    #pragma unroll
    for (int ni = 0; ni < 4; ++ni)
      acc[mi][ni] = (f32x4){0.f, 0.f, 0.f, 0.f};

  bf16x8 cF[2][4];
  bf16x8 xF[2][4];

#define STAGE_AH0(T) { const int d_=((T)&1)*16384; const int so_=(T)*64;                  \
  gload16(pA + so_,          (void*)&lds[d_ + tid * 8]);                                  \
  gload16(pA + 65536 + so_,  (void*)&lds[d_ + 4096 + tid * 8]); }
#define STAGE_AH1(T) { const int d_=((T)&1)*16384 + 8192; const int so_=(T)*64;           \
  gload16(pA + 32768 + so_,  (void*)&lds[d_ + tid * 8]);                                  \
  gload16(pA + 98304 + so_,  (void*)&lds[d_ + 4096 + tid * 8]); }
#define STAGE_BH0(T) { const int d_=32768+((T)&1)*16384; const int so_=(T)*64;            \
  gload16(pB + so_,          (void*)&lds[d_ + tid * 8]);                                  \
  gload16(pB + 32768 + so_,  (void*)&lds[d_ + 4096 + tid * 8]); }
#define STAGE_BH1(T) { const int d_=32768+((T)&1)*16384 + 8192; const int so_=(T)*64;     \
  gload16(pB + 65536 + so_,  (void*)&lds[d_ + tid * 8]);                                  \
  gload16(pB + 98304 + so_,  (void*)&lds[d_ + 4096 + tid * 8]); }

  // reads for phase pp: tile kt'=pp>>2, s'=pp&3, h'=s'>>1, ks'=s'&1, reg set pp&1
#define ISSUE_READS(pp)                                                                   \
  { const int kt_ = (pp) >> 2, s_ = (pp) & 3, h_ = s_ >> 1, ks_ = s_ & 1;                 \
    const int bo_ = (kt_ & 1) * 16384;                                                    \
    const int co_ = ks_ ? cOff1 : cOff0;                                                  \
    _Pragma("unroll")                                                                     \
    for (int q = 0; q < 4; ++q)                                                           \
      cF[(pp) & 1][q] = *(const bf16x8*)&lds[bo_ + h_ * 8192 + q * 1024 + co_];           \
    if (h_ == 0) {                                                                        \
      const int xo_ = ks_ ? xOff1 : xOff0;                                                \
      _Pragma("unroll")                                                                   \
      for (int ni = 0; ni < 4; ++ni)                                                      \
        xF[(pp) & 1][ni] = *(const bf16x8*)&lds[32768 + bo_ + ni * 1024 + xo_];           \
    } }

  // ---- prologue: tile0 fully + tile1 {A-h0, B-h0}; certify tile0; reads(0) ----
  STAGE_AH0(0); STAGE_AH1(0); STAGE_BH0(0); STAGE_BH1(0);
  STAGE_AH0(1); STAGE_BH0(1);
  asm volatile("s_waitcnt vmcnt(4)" ::: "memory");
  __builtin_amdgcn_s_barrier();
  __builtin_amdgcn_sched_barrier(0);
  ISSUE_READS(0);

  #pragma unroll
  for (int ph = 0; ph < 32; ++ph) {
    const int s = ph & 3, kt = ph >> 2;

    // counted certification before barrier (drained loads are >=2 phases old)
    if (s == 3 && ph != 31) asm volatile("s_waitcnt vmcnt(2)" ::: "memory");
    if (ph == 29)           asm volatile("s_waitcnt vmcnt(0)" ::: "memory");
    __builtin_amdgcn_s_barrier();
    __builtin_amdgcn_sched_barrier(0);

    // stage one quarter-tile (ledger: target's last reads lgkm'd before prev barrier)
    if      (s == 0 && kt <= 6) { STAGE_BH1(kt + 1); }
    else if (s == 1 && kt <= 6) { STAGE_AH1(kt + 1); }
    else if (s == 2 && kt <= 5) { STAGE_AH0(kt + 2); }
    else if (s == 3 && kt <= 5) { STAGE_BH0(kt + 2); }

    // read-ahead for ph+1 into alternate register set
    if (ph < 31) ISSUE_READS(ph + 1);

    // counted wait: phase ph's reads done, ph+1's stay outstanding
    if (ph == 31)            asm volatile("s_waitcnt lgkmcnt(0)" ::: "memory");
    else if (((ph + 1) & 2) == 0) asm volatile("s_waitcnt lgkmcnt(8)" ::: "memory");
    else                     asm volatile("s_waitcnt lgkmcnt(4)" ::: "memory");
    __builtin_amdgcn_sched_barrier(0);

    __builtin_amdgcn_s_setprio(1);
    {
      const int h = s >> 1;
      #pragma unroll
      for (int q = 0; q < 4; ++q)
        #pragma unroll
        for (int ni = 0; ni < 4; ++ni)
          acc[h * 4 + q][ni] = __builtin_amdgcn_mfma_f32_16x16x32_bf16(
              cF[ph & 1][q], xF[ph & 1][ni], acc[h * 4 + q][ni], 0, 0, 0);
    }
    __builtin_amdgcn_s_setprio(0);
  }
#undef ISSUE_READS
#undef STAGE_AH0
#undef STAGE_AH1
#undef STAGE_BH0
#undef STAGE_BH1

  // ---- epilogue: per-lane register top-3 (round-6/7 verified) ----
  // D[m=cb][n=x]: x-row = lane&15, cb = (lane>>4)*4 + reg; acc[mi] <-> cb wr*128+mi*16
#define INS(st1, st2, st3, kx)                                     \
  { uint kk_ = (kx);                                               \
    bool lt1 = kk_ < st1, lt2 = kk_ < st2, lt3 = kk_ < st3;        \
    st3 = lt3 ? (lt2 ? st2 : kk_) : st3;                           \
    st2 = lt2 ? (lt1 ? st1 : kk_) : st2;                           \
    st1 = lt1 ? kk_ : st1; }

  uint t1[4], t2[4], t3[4];
  #pragma unroll
  for (int ni = 0; ni < 4; ++ni) { t1[ni] = 0xFFFFFFFFu; t2[ni] = 0xFFFFFFFFu; t3[ni] = 0xFFFFFFFFu; }

  #pragma unroll
  for (int mi = 0; mi < 8; ++mi) {
    float cnv[4];
    *(float4*)cnv = *(const float4*)&cnorm[colBase + wr * 128 + mi * 16 + grp * 4];
    #pragma unroll
    for (int ni = 0; ni < 4; ++ni) {
      #pragma unroll
      for (int rg = 0; rg < 4; ++rg) {
        float v = cnv[rg] - 2.0f * acc[mi][ni][rg];
        uint u = __float_as_uint(v);
        u = ((int)u < 0) ? ~u : (u | 0x80000000u);
        uint key = (u & 0xFFFFFF80u) | (uint)(mi * 16 + grp * 4 + rg);
        INS(t1[ni], t2[ni], t3[ni], key);
      }
    }
  }
  #pragma unroll
  for (int ni = 0; ni < 4; ++ni) {
    #pragma unroll
    for (int mk = 16; mk <= 32; mk <<= 1) {
      uint o1 = (uint)__shfl_xor((int)t1[ni], mk, 64);
      uint o2 = (uint)__shfl_xor((int)t2[ni], mk, 64);
      uint o3 = (uint)__shfl_xor((int)t3[ni], mk, 64);
      INS(t1[ni], t2[ni], t3[ni], o1);
      INS(t1[ni], t2[ni], t3[ni], o2);
      INS(t1[ni], t2[ni], t3[ni], o3);
    }
  }
#undef INS
  if (grp == 0) {    // lanes 0..15 hold final result for their x-row
    #pragma unroll
    for (int ni = 0; ni < 4; ++ni) {
      float v1 = keyval(t1[ni]), v2 = keyval(t2[ni]), v3 = keyval(t3[ni]);
      uint i1 = t1[ni] & 127u, i2 = t2[ni] & 127u;
      uint d2 = min(255u, (uint)((v2 - v1) * 4.0f));   // floor -> conservative-low
      uint d3 = min(255u, (uint)((v3 - v1) * 4.0f));
      uint2 st;
      st.x = __float_as_uint(v1);
      st.y = i1 | (i2 << 7) | (d2 << 14) | (d3 << 22);
      int xrow = rowBase + wc * 64 + ni * 16 + l15;
      stats[(size_t)xrow * NTILES + nTile * 2 + wr] = st;
    }
  }
}

// ---------------- fp64 refinement (one wave per row) ----------------

__device__ inline void eval64(const float4& xa, const float4& xb,
                              const float* __restrict__ cb, int col,
                              double& best, int& bi, int lane) {
  const float* cr = cb + (size_t)col * DDIM + lane * 8;
  float4 ca = *(const float4*)cr;
  float4 cv = *(const float4*)(cr + 4);
  double s = 0.0, d;
  d = (double)xa.x - (double)ca.x; s += d*d;
  d = (double)xa.y - (double)ca.y; s += d*d;
  d = (double)xa.z - (double)ca.z; s += d*d;
  d = (double)xa.w - (double)ca.w; s += d*d;
  d = (double)xb.x - (double)cv.x; s += d*d;
  d = (double)xb.y - (double)cv.y; s += d*d;
  d = (double)xb.z - (double)cv.z; s += d*d;
  d = (double)xb.w - (double)cv.w; s += d*d;
  #pragma unroll
  for (int m = 1; m < 64; m <<= 1) s += shfl_xor_dbl(s, m);
  if (s < best || (s == best && col < bi)) { best = s; bi = col; }
}

__global__ __launch_bounds__(256) void k_refine(
    const float* __restrict__ x, const float* __restrict__ cb,
    const float* __restrict__ cnorm, const uint2* __restrict__ stats,
    unsigned int* __restrict__ bestOut)
{
  int n = blockIdx.x * 4 + (threadIdx.x >> 6);
  int lane = threadIdx.x & 63;
  uint2 st = stats[(size_t)n * NTILES + lane];   // lane t owns stat tile t
  float m1 = __uint_as_float(st.x);
  int   i1 = st.y & 127, i2 = (st.y >> 7) & 127;
  float m2 = m1 + ((st.y >> 14) & 255u) * 0.25f;
  float m3 = m1 + ((st.y >> 22) & 255u) * 0.25f;
  float g = m1;
  #pragma unroll
  for (int m = 1; m < 64; m <<= 1) g = fminf(g, __shfl_xor(g, m, 64));
  float T = g + MARGIN;
  unsigned long long q1 = __ballot(m1 <= T);
  unsigned long long q2 = __ballot(m2 <= T);
  unsigned long long qr = __ballot(m3 <= T);

  const float* xr = x + (size_t)n * DDIM;
  float4 xa = *(const float4*)(xr + lane * 8);
  float4 xb = *(const float4*)(xr + lane * 8 + 4);

  double best = 1e300;
  int bi = 0x7fffffff;

  while (q1) {
    int t = __ffsll(q1) - 1; q1 &= q1 - 1;
    int col = t * 128 + __shfl(i1, t, 64);
    eval64(xa, xb, cb, col, best, bi, lane);
  }
  while (q2) {
    int t = __ffsll(q2) - 1; q2 &= q2 - 1;
    int col = t * 128 + __shfl(i2, t, 64);
    eval64(xa, xb, cb, col, best, bi, lane);
  }
  while (qr) {
    int t = __ffsll(qr) - 1; qr &= qr - 1;
    for (int c2 = 0; c2 < 128; ++c2) {
      int col2 = t * 128 + c2;
      const float* cr = cb + (size_t)col2 * DDIM + lane * 8;
      float4 ca = *(const float4*)cr;
      float4 cv = *(const float4*)(cr + 4);
      float p = xa.x*ca.x + xa.y*ca.y + xa.z*ca.z + xa.w*ca.w
              + xb.x*cv.x + xb.y*cv.y + xb.z*cv.z + xb.w*cv.w;
      #pragma unroll
      for (int m = 1; m < 64; m <<= 1) p += __shfl_xor(p, m, 64);
      float s32 = cnorm[col2] - 2.0f * p;
      if (s32 <= T) {
        double s = 0.0, dd;
        dd = (double)xa.x - (double)ca.x; s += dd*dd;
        dd = (double)xa.y - (double)ca.y; s += dd*dd;
        dd = (double)xa.z - (double)ca.z; s += dd*dd;
        dd = (double)xa.w - (double)ca.w; s += dd*dd;
        dd = (double)xb.x - (double)cv.x; s += dd*dd;
        dd = (double)xb.y - (double)cv.y; s += dd*dd;
        dd = (double)xb.z - (double)cv.z; s += dd*dd;
        dd = (double)xb.w - (double)cv.w; s += dd*dd;
        #pragma unroll
        for (int m = 1; m < 64; m <<= 1) s += shfl_xor_dbl(s, m);
        if (s < best || (s == best && col2 < bi)) { best = s; bi = col2; }
      }
    }
  }
  if (lane == 0) bestOut[n] = (unsigned int)bi;
}

// ---------------- gather ----------------

__global__ __launch_bounds__(256) void k_gather(const float* __restrict__ cb,
                                                const unsigned int* __restrict__ bestIdx,
                                                float* __restrict__ out) {
  int n = blockIdx.x * 4 + (threadIdx.x >> 6);
  int lane = threadIdx.x & 63;
  unsigned int b = bestIdx[n];
  const float4* s = (const float4*)(cb + (size_t)b * DDIM);
  float4* dp = (float4*)(out + (size_t)n * DDIM);
  dp[lane * 2]     = s[lane * 2];
  dp[lane * 2 + 1] = s[lane * 2 + 1];
}

// ---------------- launch ----------------

extern "C" void kernel_launch(void* const* d_in, const int* in_sizes, int n_in,
                              void* d_out, int out_size, void* d_ws, size_t ws_size,
                              hipStream_t stream) {
  const float* x  = (const float*)d_in[0];   // [16384, 512]
  const float* cb = (const float*)d_in[1];   // [8192, 512]
  float* out = (float*)d_out;

  // d_out as scratch until gather: [0,16M) Xbf | [16M,24M) Cbf | [24M,32M) stats
  char* ob = (char*)d_out;
  u16*   Xbf   = (u16*)ob;
  u16*   Cbf   = (u16*)(ob + 16ull * 1024 * 1024);
  uint2* stats = (uint2*)(ob + 24ull * 1024 * 1024);

  char* wsb = (char*)d_ws;
  float* cnorm = (float*)wsb;                            // 32 KB
  unsigned int* bestIdx = (unsigned int*)(wsb + 32 * 1024);

  (void)hipFuncSetAttribute((const void*)k_gemm_min,
                            hipFuncAttributeMaxDynamicSharedMemorySize, 131072);

  k_conv_x  <<<4096, 256, 0, stream>>>(x, Xbf);
  k_conv_cb <<<2048, 256, 0, stream>>>(cb, Cbf, cnorm);
  k_gemm_min<<<2048, 512, 131072, stream>>>(Xbf, Cbf, cnorm, stats);
  k_refine  <<<4096, 256, 0, stream>>>(x, cb, cnorm, stats, bestIdx);
  k_gather  <<<4096, 256, 0, stream>>>(cb, bestIdx, out);
}